// Round 1
// baseline (3945.134 us; speedup 1.0000x reference)
//
#include <hip/hip_runtime.h>
#include <math.h>

#define TS 64
#define KT 16

__device__ __forceinline__ float waveReduceSum(float v){
  #pragma unroll
  for(int o=32;o>0;o>>=1) v += __shfl_down(v,o,64);
  return v;
}
__device__ __forceinline__ float waveReduceMax(float v){
  #pragma unroll
  for(int o=32;o>0;o>>=1) v = fmaxf(v, __shfl_down(v,o,64));
  return v;
}

__device__ __forceinline__ float atomicMaxFloat(float* addr, float value){
  if(value >= 0.f)
    return __int_as_float(atomicMax((int*)addr, __float_as_int(value)));
  else
    return __uint_as_float(atomicMin((unsigned int*)addr, __float_as_uint(value)));
}

// ---------------- GEMM: C[M,N] = A[M,K] @ B[K,N] (+bias) ----------------
__global__ __launch_bounds__(256) void gemm_bias(const float* __restrict__ A,
                                                 const float* __restrict__ B,
                                                 const float* __restrict__ bias,
                                                 float* __restrict__ C,
                                                 int M, int K, int N){
  __shared__ float As[KT][TS+1];
  __shared__ float Bs[KT][TS+1];
  int t = threadIdx.x;
  int tx = t & 15, ty = t >> 4;
  int bm = blockIdx.y * TS, bn = blockIdx.x * TS;
  float acc[4][4] = {{0.f}};
  for(int k0=0;k0<K;k0+=KT){
    #pragma unroll
    for(int i=t;i<TS*KT;i+=256){
      int m = i >> 4, kk = i & 15;
      As[kk][m] = A[(bm+m)*K + k0 + kk];
      int k2 = i >> 6, nn = i & 63;
      Bs[k2][nn] = B[(k0+k2)*N + bn + nn];
    }
    __syncthreads();
    #pragma unroll
    for(int kk=0;kk<KT;kk++){
      float a[4], b[4];
      #pragma unroll
      for(int i=0;i<4;i++) a[i]=As[kk][ty*4+i];
      #pragma unroll
      for(int j=0;j<4;j++) b[j]=Bs[kk][tx*4+j];
      #pragma unroll
      for(int i=0;i<4;i++)
        #pragma unroll
        for(int j=0;j<4;j++) acc[i][j] += a[i]*b[j];
    }
    __syncthreads();
  }
  #pragma unroll
  for(int i=0;i<4;i++){
    int m = bm + ty*4 + i;
    #pragma unroll
    for(int j=0;j<4;j++){
      int n = bn + tx*4 + j;
      float v = acc[i][j];
      if(bias) v += bias[n];
      C[m*N+n] = v;
    }
  }
}

// --------- per-node attention coefficients: als/ald [N,H] ---------
__global__ __launch_bounds__(256) void attn_coef(const float* __restrict__ xl,
                                                 const float* __restrict__ a_s,
                                                 const float* __restrict__ a_d,
                                                 float* __restrict__ als,
                                                 float* __restrict__ ald,
                                                 int H, int C){
  int n = blockIdx.x, t = threadIdx.x;
  int D = H*C;
  __shared__ float s1[4], s2[4];
  int lane = t & 63, wid = t >> 6;
  for(int h=0;h<H;h++){
    float ps=0.f, pd=0.f;
    for(int c=t;c<C;c+=256){
      float v = xl[n*D + h*C + c];
      ps += v * a_s[h*C+c];
      pd += v * a_d[h*C+c];
    }
    ps = waveReduceSum(ps);
    pd = waveReduceSum(pd);
    if(lane==0){ s1[wid]=ps; s2[wid]=pd; }
    __syncthreads();
    if(t==0){
      float u=0.f,w=0.f;
      #pragma unroll
      for(int i=0;i<4;i++){u+=s1[i]; w+=s2[i];}
      als[n*H+h]=u; ald[n*H+h]=w;
    }
    __syncthreads();
  }
}

// --------- init segment buffers ---------
__global__ void init_seg(float* mseg, float* dseg, int nh, float* aggr, int nd){
  int i = blockIdx.x*256 + threadIdx.x;
  if(i<nh){ mseg[i]=-INFINITY; dseg[i]=0.f; }
  for(int j=i;j<nd;j+=gridDim.x*256) aggr[j]=0.f;
}

// --------- edge pass 1: alpha + segment max ---------
__global__ void edge_alpha(const int* __restrict__ ei, int E, int Etot, int logH,
                           const float* __restrict__ als, const float* __restrict__ ald,
                           float* __restrict__ alpha, float* __restrict__ mseg){
  int H = 1<<logH;
  int idx = blockIdx.x*256+threadIdx.x;
  if(idx >= (Etot<<logH)) return;
  int e = idx >> logH, h = idx & (H-1);
  int s,d;
  if(e<E){ s=ei[e]&4095; d=ei[E+e]&4095; } else { s=d=e-E; }
  float a = als[(s<<logH)+h] + ald[(d<<logH)+h];
  a = a>0.f ? a : 0.2f*a;
  alpha[idx]=a;
  atomicMaxFloat(&mseg[(d<<logH)+h], a);
}

// --------- edge pass 2: exp + segment sum ---------
__global__ void edge_expsum(const int* __restrict__ ei, int E, int Etot, int logH,
                            float* __restrict__ alpha, const float* __restrict__ mseg,
                            float* __restrict__ dseg){
  int H = 1<<logH;
  int idx = blockIdx.x*256+threadIdx.x;
  if(idx >= (Etot<<logH)) return;
  int e = idx >> logH, h = idx & (H-1);
  int d = (e<E) ? (ei[E+e]&4095) : (e-E);
  float p = expf(alpha[idx] - mseg[(d<<logH)+h]);
  alpha[idx] = p;
  atomicAdd(&dseg[(d<<logH)+h], p);
}

// --------- edge pass 3: weighted message aggregation ---------
__global__ void edge_message(const int* __restrict__ ei, int E, int Etot,
                             int logD, int logC, int logH,
                             const float* __restrict__ p, const float* __restrict__ dseg,
                             const float* __restrict__ xl, float* __restrict__ aggr){
  int total = Etot << logD;
  int idx = blockIdx.x*256+threadIdx.x;
  if(idx>=total) return;
  int e = idx >> logD, j = idx & ((1<<logD)-1);
  int h = j >> logC;
  int s,d;
  if(e<E){ s=ei[e]&4095; d=ei[E+e]&4095; } else { s=d=e-E; }
  float w = p[(e<<logH)+h] / (dseg[(d<<logH)+h] + 1e-16f);
  atomicAdd(&aggr[(d<<logD)+j], w * xl[(s<<logD)+j]);
}

// --------- finalize: bias + (ELU) + LayerNorm (+residual) ---------
__global__ __launch_bounds__(256) void finalize_ln(const float* __restrict__ aggr,
                                                   const float* __restrict__ bias,
                                                   const float* __restrict__ g,
                                                   const float* __restrict__ be,
                                                   const float* __restrict__ res,
                                                   float* __restrict__ out,
                                                   int D, int do_elu){
  int n = blockIdx.x, t = threadIdx.x;
  __shared__ float sh[4];
  float v[2];
  int cnt = D >> 8;  // 1 (D=256) or 2 (D=512)
  float sum = 0.f;
  for(int i=0;i<cnt;i++){
    int j = t + (i<<8);
    float x = aggr[n*D+j] + bias[j];
    if(do_elu) x = x>0.f ? x : expm1f(x);
    v[i]=x; sum += x;
  }
  sum = waveReduceSum(sum);
  int lane=t&63, wid=t>>6;
  if(lane==0) sh[wid]=sum;
  __syncthreads();
  float mean = (sh[0]+sh[1]+sh[2]+sh[3]) / (float)D;
  __syncthreads();
  float vs=0.f;
  for(int i=0;i<cnt;i++){ float dd=v[i]-mean; vs+=dd*dd; }
  vs = waveReduceSum(vs);
  if(lane==0) sh[wid]=vs;
  __syncthreads();
  float var = (sh[0]+sh[1]+sh[2]+sh[3]) / (float)D;
  float inv = rsqrtf(var + 1e-5f);
  for(int i=0;i<cnt;i++){
    int j = t + (i<<8);
    float y = (v[i]-mean)*inv*g[j] + be[j];
    if(res) y += res[n*D+j];
    out[n*D+j]=y;
  }
}

// --------- dense MHA: one block per (query, head), scores in LDS ---------
__global__ __launch_bounds__(256) void attention(const float* __restrict__ Q,
                                                 const float* __restrict__ K,
                                                 const float* __restrict__ V,
                                                 float* __restrict__ O, int S){
  const int D=256, dk=32;
  int q = blockIdx.x, h = blockIdx.y;
  int t = threadIdx.x;
  __shared__ float sc[4096];
  __shared__ float qs[32];
  __shared__ float sh[4];
  __shared__ float pv[256];
  if(t<dk) qs[t] = Q[q*D + h*dk + t];
  __syncthreads();
  const float scale = 0.17677669529663687f; // 1/sqrt(32)
  float lmax = -INFINITY;
  for(int k=t;k<S;k+=256){
    const float* kp = K + k*D + h*dk;
    float s=0.f;
    #pragma unroll
    for(int d=0;d<dk;d++) s += qs[d]*kp[d];
    s *= scale;
    sc[k]=s;
    lmax = fmaxf(lmax, s);
  }
  lmax = waveReduceMax(lmax);
  int lane=t&63, wid=t>>6;
  if(lane==0) sh[wid]=lmax;
  __syncthreads();
  float m = fmaxf(fmaxf(sh[0],sh[1]), fmaxf(sh[2],sh[3]));
  __syncthreads();
  float lsum=0.f;
  for(int k=t;k<S;k+=256){
    float p = expf(sc[k]-m);
    sc[k]=p;
    lsum += p;
  }
  lsum = waveReduceSum(lsum);
  if(lane==0) sh[wid]=lsum;
  __syncthreads();
  float l = sh[0]+sh[1]+sh[2]+sh[3];
  // P @ V
  int d = t & 31, gr = t >> 5;  // 8 groups of 32
  float acc=0.f;
  for(int k=gr;k<S;k+=8){
    acc += sc[k] * V[k*D + h*dk + d];
  }
  pv[t]=acc;
  __syncthreads();
  if(t<32){
    float o=0.f;
    #pragma unroll
    for(int gg=0;gg<8;gg++) o += pv[gg*32 + t];
    O[q*D + h*dk + t] = o / l;
  }
}

extern "C" void kernel_launch(void* const* d_in, const int* in_sizes, int n_in,
                              void* d_out, int out_size, void* d_ws, size_t ws_size,
                              hipStream_t stream) {
  const float* x   = (const float*)d_in[0];
  const int*   ei  = (const int*)d_in[1];
  const float* W0  = (const float*)d_in[2];
  const float* as0 = (const float*)d_in[3];
  const float* ad0 = (const float*)d_in[4];
  const float* b0  = (const float*)d_in[5];
  const float* W1  = (const float*)d_in[6];
  const float* as1 = (const float*)d_in[7];
  const float* ad1 = (const float*)d_in[8];
  const float* b1  = (const float*)d_in[9];
  const float* W2  = (const float*)d_in[10];
  const float* as2 = (const float*)d_in[11];
  const float* ad2 = (const float*)d_in[12];
  const float* b2  = (const float*)d_in[13];
  const float* g0  = (const float*)d_in[14];
  const float* be0 = (const float*)d_in[15];
  const float* g1  = (const float*)d_in[16];
  const float* be1 = (const float*)d_in[17];
  const float* g2  = (const float*)d_in[18];
  const float* be2 = (const float*)d_in[19];
  const float* wq  = (const float*)d_in[20];
  const float* bq  = (const float*)d_in[21];
  const float* wk  = (const float*)d_in[22];
  const float* bk  = (const float*)d_in[23];
  const float* wv  = (const float*)d_in[24];
  const float* bv  = (const float*)d_in[25];
  const float* wo  = (const float*)d_in[26];
  const float* bo  = (const float*)d_in[27];
  float* out = (float*)d_out;

  const int N = 4096;
  const int E = in_sizes[1] / 2;
  const int Etot = E + N;

  float* ws = (float*)d_ws;
  float* xl   = ws;  ws += N*512;
  float* aggr = ws;  ws += N*512;
  float* h0   = ws;  ws += N*512;
  float* h1   = ws;  ws += N*512;
  float* h2   = ws;  ws += N*256;
  float* Qb   = ws;  ws += N*256;
  float* Kb   = ws;  ws += N*256;
  float* Vb   = ws;  ws += N*256;
  float* ao   = ws;  ws += N*256;
  float* als  = ws;  ws += N*4;
  float* ald  = ws;  ws += N*4;
  float* mseg = ws;  ws += N*4;
  float* dseg = ws;  ws += N*4;
  float* eexp = ws;  ws += Etot*4;

  int gEH4 = ((Etot*4)+255)/256;
  int gEH1 = (Etot+255)/256;

  // ---------- GAT layer 0: 128 -> 4x128 (512) ----------
  gemm_bias<<<dim3(512/TS, N/TS), 256, 0, stream>>>(x, W0, nullptr, xl, N, 128, 512);
  attn_coef<<<N, 256, 0, stream>>>(xl, as0, ad0, als, ald, 4, 128);
  init_seg<<<(N*512+255)/256, 256, 0, stream>>>(mseg, dseg, N*4, aggr, N*512);
  edge_alpha<<<gEH4, 256, 0, stream>>>(ei, E, Etot, 2, als, ald, eexp, mseg);
  edge_expsum<<<gEH4, 256, 0, stream>>>(ei, E, Etot, 2, eexp, mseg, dseg);
  edge_message<<<((Etot*512)+255)/256, 256, 0, stream>>>(ei, E, Etot, 9, 7, 2, eexp, dseg, xl, aggr);
  finalize_ln<<<N, 256, 0, stream>>>(aggr, b0, g0, be0, nullptr, h0, 512, 1);

  // ---------- GAT layer 1: 512 -> 4x128 (512), residual ----------
  gemm_bias<<<dim3(512/TS, N/TS), 256, 0, stream>>>(h0, W1, nullptr, xl, N, 512, 512);
  attn_coef<<<N, 256, 0, stream>>>(xl, as1, ad1, als, ald, 4, 128);
  init_seg<<<(N*512+255)/256, 256, 0, stream>>>(mseg, dseg, N*4, aggr, N*512);
  edge_alpha<<<gEH4, 256, 0, stream>>>(ei, E, Etot, 2, als, ald, eexp, mseg);
  edge_expsum<<<gEH4, 256, 0, stream>>>(ei, E, Etot, 2, eexp, mseg, dseg);
  edge_message<<<((Etot*512)+255)/256, 256, 0, stream>>>(ei, E, Etot, 9, 7, 2, eexp, dseg, xl, aggr);
  finalize_ln<<<N, 256, 0, stream>>>(aggr, b1, g1, be1, h0, h1, 512, 1);

  // ---------- GAT layer 2: 512 -> 1x256, no ELU ----------
  gemm_bias<<<dim3(256/TS, N/TS), 256, 0, stream>>>(h1, W2, nullptr, xl, N, 512, 256);
  attn_coef<<<N, 256, 0, stream>>>(xl, as2, ad2, als, ald, 1, 256);
  init_seg<<<(N*256+255)/256, 256, 0, stream>>>(mseg, dseg, N*1, aggr, N*256);
  edge_alpha<<<gEH1, 256, 0, stream>>>(ei, E, Etot, 0, als, ald, eexp, mseg);
  edge_expsum<<<gEH1, 256, 0, stream>>>(ei, E, Etot, 0, eexp, mseg, dseg);
  edge_message<<<((Etot*256)+255)/256, 256, 0, stream>>>(ei, E, Etot, 8, 8, 0, eexp, dseg, xl, aggr);
  finalize_ln<<<N, 256, 0, stream>>>(aggr, b2, g2, be2, nullptr, h2, 256, 0);

  // ---------- dense MHA over 4096 nodes ----------
  gemm_bias<<<dim3(256/TS, N/TS), 256, 0, stream>>>(h2, wq, bq, Qb, N, 256, 256);
  gemm_bias<<<dim3(256/TS, N/TS), 256, 0, stream>>>(h2, wk, bk, Kb, N, 256, 256);
  gemm_bias<<<dim3(256/TS, N/TS), 256, 0, stream>>>(h2, wv, bv, Vb, N, 256, 256);
  attention<<<dim3(N, 8), 256, 0, stream>>>(Qb, Kb, Vb, ao, N);
  gemm_bias<<<dim3(256/TS, N/TS), 256, 0, stream>>>(ao, wo, bo, out, N, 256, 256);
}

// Round 2
// 1628.515 us; speedup vs baseline: 2.4225x; 2.4225x over previous
//
#include <hip/hip_runtime.h>
#include <math.h>

#define TS 64
#define KT 16

__device__ __forceinline__ float waveReduceSum(float v){
  #pragma unroll
  for(int o=32;o>0;o>>=1) v += __shfl_down(v,o,64);
  return v;
}

__device__ __forceinline__ float atomicMaxFloat(float* addr, float value){
  if(value >= 0.f)
    return __int_as_float(atomicMax((int*)addr, __float_as_int(value)));
  else
    return __uint_as_float(atomicMin((unsigned int*)addr, __float_as_uint(value)));
}

// ---------------- GEMM: C[M,N] = A[M,K] @ B[K,N] (+bias) ----------------
__global__ __launch_bounds__(256) void gemm_bias(const float* __restrict__ A,
                                                 const float* __restrict__ B,
                                                 const float* __restrict__ bias,
                                                 float* __restrict__ C,
                                                 int M, int K, int N){
  __shared__ float As[KT][TS+1];
  __shared__ float Bs[KT][TS+1];
  int t = threadIdx.x;
  int tx = t & 15, ty = t >> 4;
  int bm = blockIdx.y * TS, bn = blockIdx.x * TS;
  float acc[4][4] = {{0.f}};
  for(int k0=0;k0<K;k0+=KT){
    #pragma unroll
    for(int i=t;i<TS*KT;i+=256){
      int m = i >> 4, kk = i & 15;
      As[kk][m] = A[(bm+m)*K + k0 + kk];
      int k2 = i >> 6, nn = i & 63;
      Bs[k2][nn] = B[(k0+k2)*N + bn + nn];
    }
    __syncthreads();
    #pragma unroll
    for(int kk=0;kk<KT;kk++){
      float a[4], b[4];
      #pragma unroll
      for(int i=0;i<4;i++) a[i]=As[kk][ty*4+i];
      #pragma unroll
      for(int j=0;j<4;j++) b[j]=Bs[kk][tx*4+j];
      #pragma unroll
      for(int i=0;i<4;i++)
        #pragma unroll
        for(int j=0;j<4;j++) acc[i][j] += a[i]*b[j];
    }
    __syncthreads();
  }
  #pragma unroll
  for(int i=0;i<4;i++){
    int m = bm + ty*4 + i;
    #pragma unroll
    for(int j=0;j<4;j++){
      int n = bn + tx*4 + j;
      float v = acc[i][j];
      if(bias) v += bias[n];
      C[m*N+n] = v;
    }
  }
}

// --------- per-node attention coefficients: als/ald [N,H] ---------
__global__ __launch_bounds__(256) void attn_coef(const float* __restrict__ xl,
                                                 const float* __restrict__ a_s,
                                                 const float* __restrict__ a_d,
                                                 float* __restrict__ als,
                                                 float* __restrict__ ald,
                                                 int H, int C){
  int n = blockIdx.x, t = threadIdx.x;
  int D = H*C;
  __shared__ float s1[4], s2[4];
  int lane = t & 63, wid = t >> 6;
  for(int h=0;h<H;h++){
    float ps=0.f, pd=0.f;
    for(int c=t;c<C;c+=256){
      float v = xl[n*D + h*C + c];
      ps += v * a_s[h*C+c];
      pd += v * a_d[h*C+c];
    }
    ps = waveReduceSum(ps);
    pd = waveReduceSum(pd);
    if(lane==0){ s1[wid]=ps; s2[wid]=pd; }
    __syncthreads();
    if(t==0){
      float u=0.f,w=0.f;
      #pragma unroll
      for(int i=0;i<4;i++){u+=s1[i]; w+=s2[i];}
      als[n*H+h]=u; ald[n*H+h]=w;
    }
    __syncthreads();
  }
}

// --------- init segment buffers ---------
__global__ void init_seg(float* mseg, float* dseg, int nh, float* aggr, int nd){
  int i = blockIdx.x*256 + threadIdx.x;
  if(i<nh){ mseg[i]=-INFINITY; dseg[i]=0.f; }
  for(int j=i;j<nd;j+=gridDim.x*256) aggr[j]=0.f;
}

// --------- edge pass 1: alpha + segment max ---------
__global__ void edge_alpha(const int* __restrict__ ei, int E, int Etot, int logH,
                           const float* __restrict__ als, const float* __restrict__ ald,
                           float* __restrict__ alpha, float* __restrict__ mseg){
  int H = 1<<logH;
  int idx = blockIdx.x*256+threadIdx.x;
  if(idx >= (Etot<<logH)) return;
  int e = idx >> logH, h = idx & (H-1);
  int s,d;
  if(e<E){ s=ei[e]&4095; d=ei[E+e]&4095; } else { s=d=e-E; }
  float a = als[(s<<logH)+h] + ald[(d<<logH)+h];
  a = a>0.f ? a : 0.2f*a;
  alpha[idx]=a;
  atomicMaxFloat(&mseg[(d<<logH)+h], a);
}

// --------- edge pass 2: exp + segment sum ---------
__global__ void edge_expsum(const int* __restrict__ ei, int E, int Etot, int logH,
                            float* __restrict__ alpha, const float* __restrict__ mseg,
                            float* __restrict__ dseg){
  int H = 1<<logH;
  int idx = blockIdx.x*256+threadIdx.x;
  if(idx >= (Etot<<logH)) return;
  int e = idx >> logH, h = idx & (H-1);
  int d = (e<E) ? (ei[E+e]&4095) : (e-E);
  float p = expf(alpha[idx] - mseg[(d<<logH)+h]);
  alpha[idx] = p;
  atomicAdd(&dseg[(d<<logH)+h], p);
}

// --------- edge pass 3: weighted message aggregation ---------
__global__ void edge_message(const int* __restrict__ ei, int E, int Etot,
                             int logD, int logC, int logH,
                             const float* __restrict__ p, const float* __restrict__ dseg,
                             const float* __restrict__ xl, float* __restrict__ aggr){
  int total = Etot << logD;
  int idx = blockIdx.x*256+threadIdx.x;
  if(idx>=total) return;
  int e = idx >> logD, j = idx & ((1<<logD)-1);
  int h = j >> logC;
  int s,d;
  if(e<E){ s=ei[e]&4095; d=ei[E+e]&4095; } else { s=d=e-E; }
  float w = p[(e<<logH)+h] / (dseg[(d<<logH)+h] + 1e-16f);
  atomicAdd(&aggr[(d<<logD)+j], w * xl[(s<<logD)+j]);
}

// --------- finalize: bias + (ELU) + LayerNorm (+residual) ---------
__global__ __launch_bounds__(256) void finalize_ln(const float* __restrict__ aggr,
                                                   const float* __restrict__ bias,
                                                   const float* __restrict__ g,
                                                   const float* __restrict__ be,
                                                   const float* __restrict__ res,
                                                   float* __restrict__ out,
                                                   int D, int do_elu){
  int n = blockIdx.x, t = threadIdx.x;
  __shared__ float sh[4];
  float v[2];
  int cnt = D >> 8;  // 1 (D=256) or 2 (D=512)
  float sum = 0.f;
  for(int i=0;i<cnt;i++){
    int j = t + (i<<8);
    float x = aggr[n*D+j] + bias[j];
    if(do_elu) x = x>0.f ? x : expm1f(x);
    v[i]=x; sum += x;
  }
  sum = waveReduceSum(sum);
  int lane=t&63, wid=t>>6;
  if(lane==0) sh[wid]=sum;
  __syncthreads();
  float mean = (sh[0]+sh[1]+sh[2]+sh[3]) / (float)D;
  __syncthreads();
  float vs=0.f;
  for(int i=0;i<cnt;i++){ float dd=v[i]-mean; vs+=dd*dd; }
  vs = waveReduceSum(vs);
  if(lane==0) sh[wid]=vs;
  __syncthreads();
  float var = (sh[0]+sh[1]+sh[2]+sh[3]) / (float)D;
  float inv = rsqrtf(var + 1e-5f);
  for(int i=0;i<cnt;i++){
    int j = t + (i<<8);
    float y = (v[i]-mean)*inv*g[j] + be[j];
    if(res) y += res[n*D+j];
    out[n*D+j]=y;
  }
}

// --------- dense MHA, flash-style: block = (64-query tile, head) ---------
// No running max needed: LayerNorm bounds |q|,|k| (row norm ~16), score std ~5,
// exp cannot overflow fp32 (needs s>88). softmax(s) == softmax(s - m) exactly.
__global__ __launch_bounds__(256) void attention2(const float* __restrict__ Q,
                                                  const float* __restrict__ K,
                                                  const float* __restrict__ V,
                                                  float* __restrict__ O, int S){
  const int D = 256;
  int qb = blockIdx.x * 64;
  int h  = blockIdx.y;
  int t  = threadIdx.x;
  int tx = t & 15, ty = t >> 4;
  int d8 = t & 31;       // dim lane for staging
  int i8 = t >> 5;       // 0..7

  __shared__ float Qs[32][68];   // [dim][query]  (68: b128-aligned, low conflict)
  __shared__ float Ks[32][68];   // [dim][key]
  __shared__ float Vs[64][36];   // [key][dim]
  __shared__ float Ps[64][68];   // [query][key]

  // stage Q transposed (once)
  #pragma unroll
  for(int r=0;r<8;r++){
    int q = r*8 + i8;
    Qs[d8][q] = Q[(qb+q)*D + h*32 + d8];
  }

  const float scale = 0.17677669529663687f; // 1/sqrt(32)
  float o[4][2] = {{0.f}};
  float l[4] = {0.f,0.f,0.f,0.f};

  for(int kt=0; kt<S; kt+=64){
    // stage K (transposed) and V (row-major)
    #pragma unroll
    for(int r=0;r<8;r++){
      int k = r*8 + i8;
      Ks[d8][k] = K[(kt+k)*D + h*32 + d8];
      Vs[k][d8] = V[(kt+k)*D + h*32 + d8];
    }
    __syncthreads();

    // S-tile: 64x64, per-thread 4x4
    float s[4][4] = {{0.f}};
    #pragma unroll
    for(int kk=0;kk<32;kk++){
      float4 a = *(const float4*)&Qs[kk][ty*4];
      float4 b = *(const float4*)&Ks[kk][tx*4];
      s[0][0]+=a.x*b.x; s[0][1]+=a.x*b.y; s[0][2]+=a.x*b.z; s[0][3]+=a.x*b.w;
      s[1][0]+=a.y*b.x; s[1][1]+=a.y*b.y; s[1][2]+=a.y*b.z; s[1][3]+=a.y*b.w;
      s[2][0]+=a.z*b.x; s[2][1]+=a.z*b.y; s[2][2]+=a.z*b.z; s[2][3]+=a.z*b.w;
      s[3][0]+=a.w*b.x; s[3][1]+=a.w*b.y; s[3][2]+=a.w*b.z; s[3][3]+=a.w*b.w;
    }
    // exp + row-sum partials + write P tile
    #pragma unroll
    for(int i=0;i<4;i++){
      float4 p;
      p.x = expf(s[i][0]*scale);
      p.y = expf(s[i][1]*scale);
      p.z = expf(s[i][2]*scale);
      p.w = expf(s[i][3]*scale);
      l[i] += p.x + p.y + p.z + p.w;
      *(float4*)&Ps[ty*4+i][tx*4] = p;
    }
    __syncthreads();

    // O-tile: 64x32, per-thread 4 rows x 2 cols; O += P @ V
    #pragma unroll
    for(int kk=0;kk<64;kk+=4){
      float4 a0 = *(const float4*)&Ps[ty*4+0][kk];
      float4 a1 = *(const float4*)&Ps[ty*4+1][kk];
      float4 a2 = *(const float4*)&Ps[ty*4+2][kk];
      float4 a3 = *(const float4*)&Ps[ty*4+3][kk];
      #pragma unroll
      for(int c=0;c<4;c++){
        float2 b = *(const float2*)&Vs[kk+c][tx*2];
        float av0 = c==0?a0.x:c==1?a0.y:c==2?a0.z:a0.w;
        float av1 = c==0?a1.x:c==1?a1.y:c==2?a1.z:a1.w;
        float av2 = c==0?a2.x:c==1?a2.y:c==2?a2.z:a2.w;
        float av3 = c==0?a3.x:c==1?a3.y:c==2?a3.z:a3.w;
        o[0][0]+=av0*b.x; o[0][1]+=av0*b.y;
        o[1][0]+=av1*b.x; o[1][1]+=av1*b.y;
        o[2][0]+=av2*b.x; o[2][1]+=av2*b.y;
        o[3][0]+=av3*b.x; o[3][1]+=av3*b.y;
      }
    }
    __syncthreads();
  }

  // reduce l across the 16 tx lanes of each ty group (within-wave xor shuffle)
  #pragma unroll
  for(int i=0;i<4;i++){
    float li = l[i];
    li += __shfl_xor(li, 1, 64);
    li += __shfl_xor(li, 2, 64);
    li += __shfl_xor(li, 4, 64);
    li += __shfl_xor(li, 8, 64);
    l[i] = li;
  }
  #pragma unroll
  for(int i=0;i<4;i++){
    float inv = 1.f / l[i];
    int q = qb + ty*4 + i;
    O[q*D + h*32 + tx*2 + 0] = o[i][0]*inv;
    O[q*D + h*32 + tx*2 + 1] = o[i][1]*inv;
  }
}

extern "C" void kernel_launch(void* const* d_in, const int* in_sizes, int n_in,
                              void* d_out, int out_size, void* d_ws, size_t ws_size,
                              hipStream_t stream) {
  const float* x   = (const float*)d_in[0];
  const int*   ei  = (const int*)d_in[1];
  const float* W0  = (const float*)d_in[2];
  const float* as0 = (const float*)d_in[3];
  const float* ad0 = (const float*)d_in[4];
  const float* b0  = (const float*)d_in[5];
  const float* W1  = (const float*)d_in[6];
  const float* as1 = (const float*)d_in[7];
  const float* ad1 = (const float*)d_in[8];
  const float* b1  = (const float*)d_in[9];
  const float* W2  = (const float*)d_in[10];
  const float* as2 = (const float*)d_in[11];
  const float* ad2 = (const float*)d_in[12];
  const float* b2  = (const float*)d_in[13];
  const float* g0  = (const float*)d_in[14];
  const float* be0 = (const float*)d_in[15];
  const float* g1  = (const float*)d_in[16];
  const float* be1 = (const float*)d_in[17];
  const float* g2  = (const float*)d_in[18];
  const float* be2 = (const float*)d_in[19];
  const float* wq  = (const float*)d_in[20];
  const float* bq  = (const float*)d_in[21];
  const float* wk  = (const float*)d_in[22];
  const float* bk  = (const float*)d_in[23];
  const float* wv  = (const float*)d_in[24];
  const float* bv  = (const float*)d_in[25];
  const float* wo  = (const float*)d_in[26];
  const float* bo  = (const float*)d_in[27];
  float* out = (float*)d_out;

  const int N = 4096;
  const int E = in_sizes[1] / 2;
  const int Etot = E + N;

  float* ws = (float*)d_ws;
  float* xl   = ws;  ws += N*512;
  float* aggr = ws;  ws += N*512;
  float* h0   = ws;  ws += N*512;
  float* h1   = ws;  ws += N*512;
  float* h2   = ws;  ws += N*256;
  float* Qb   = ws;  ws += N*256;
  float* Kb   = ws;  ws += N*256;
  float* Vb   = ws;  ws += N*256;
  float* ao   = ws;  ws += N*256;
  float* als  = ws;  ws += N*4;
  float* ald  = ws;  ws += N*4;
  float* mseg = ws;  ws += N*4;
  float* dseg = ws;  ws += N*4;
  float* eexp = ws;  ws += Etot*4;

  int gEH4 = ((Etot*4)+255)/256;
  int gEH1 = (Etot+255)/256;

  // ---------- GAT layer 0: 128 -> 4x128 (512) ----------
  gemm_bias<<<dim3(512/TS, N/TS), 256, 0, stream>>>(x, W0, nullptr, xl, N, 128, 512);
  attn_coef<<<N, 256, 0, stream>>>(xl, as0, ad0, als, ald, 4, 128);
  init_seg<<<(N*512+255)/256, 256, 0, stream>>>(mseg, dseg, N*4, aggr, N*512);
  edge_alpha<<<gEH4, 256, 0, stream>>>(ei, E, Etot, 2, als, ald, eexp, mseg);
  edge_expsum<<<gEH4, 256, 0, stream>>>(ei, E, Etot, 2, eexp, mseg, dseg);
  edge_message<<<((Etot*512)+255)/256, 256, 0, stream>>>(ei, E, Etot, 9, 7, 2, eexp, dseg, xl, aggr);
  finalize_ln<<<N, 256, 0, stream>>>(aggr, b0, g0, be0, nullptr, h0, 512, 1);

  // ---------- GAT layer 1: 512 -> 4x128 (512), residual ----------
  gemm_bias<<<dim3(512/TS, N/TS), 256, 0, stream>>>(h0, W1, nullptr, xl, N, 512, 512);
  attn_coef<<<N, 256, 0, stream>>>(xl, as1, ad1, als, ald, 4, 128);
  init_seg<<<(N*512+255)/256, 256, 0, stream>>>(mseg, dseg, N*4, aggr, N*512);
  edge_alpha<<<gEH4, 256, 0, stream>>>(ei, E, Etot, 2, als, ald, eexp, mseg);
  edge_expsum<<<gEH4, 256, 0, stream>>>(ei, E, Etot, 2, eexp, mseg, dseg);
  edge_message<<<((Etot*512)+255)/256, 256, 0, stream>>>(ei, E, Etot, 9, 7, 2, eexp, dseg, xl, aggr);
  finalize_ln<<<N, 256, 0, stream>>>(aggr, b1, g1, be1, h0, h1, 512, 1);

  // ---------- GAT layer 2: 512 -> 1x256, no ELU ----------
  gemm_bias<<<dim3(256/TS, N/TS), 256, 0, stream>>>(h1, W2, nullptr, xl, N, 512, 256);
  attn_coef<<<N, 256, 0, stream>>>(xl, as2, ad2, als, ald, 1, 256);
  init_seg<<<(N*256+255)/256, 256, 0, stream>>>(mseg, dseg, N*1, aggr, N*256);
  edge_alpha<<<gEH1, 256, 0, stream>>>(ei, E, Etot, 0, als, ald, eexp, mseg);
  edge_expsum<<<gEH1, 256, 0, stream>>>(ei, E, Etot, 0, eexp, mseg, dseg);
  edge_message<<<((Etot*256)+255)/256, 256, 0, stream>>>(ei, E, Etot, 8, 8, 0, eexp, dseg, xl, aggr);
  finalize_ln<<<N, 256, 0, stream>>>(aggr, b2, g2, be2, nullptr, h2, 256, 0);

  // ---------- dense MHA over 4096 nodes ----------
  gemm_bias<<<dim3(256/TS, N/TS), 256, 0, stream>>>(h2, wq, bq, Qb, N, 256, 256);
  gemm_bias<<<dim3(256/TS, N/TS), 256, 0, stream>>>(h2, wk, bk, Kb, N, 256, 256);
  gemm_bias<<<dim3(256/TS, N/TS), 256, 0, stream>>>(h2, wv, bv, Vb, N, 256, 256);
  attention2<<<dim3(N/64, 8), 256, 0, stream>>>(Qb, Kb, Vb, ao, N);
  gemm_bias<<<dim3(256/TS, N/TS), 256, 0, stream>>>(ao, wo, bo, out, N, 256, 256);
}

// Round 3
// 731.207 us; speedup vs baseline: 5.3954x; 2.2272x over previous
//
#include <hip/hip_runtime.h>
#include <math.h>

#define TS 64
#define KT 16

typedef __attribute__((ext_vector_type(8))) short short8;
typedef __attribute__((ext_vector_type(4))) float float4v;

__device__ __forceinline__ float waveReduceSum(float v){
  #pragma unroll
  for(int o=32;o>0;o>>=1) v += __shfl_down(v,o,64);
  return v;
}

__device__ __forceinline__ unsigned short f2bf(float f){
  unsigned int u = __float_as_uint(f);
  return (unsigned short)((u + 0x7FFFu + ((u>>16)&1u)) >> 16);
}

// ---------------- GEMM: C[M,N] = A[M,K] @ B[K,N] (+bias) ----------------
// If Cbf != null, write bf16 output instead of fp32.
__global__ __launch_bounds__(256) void gemm_bias(const float* __restrict__ A,
                                                 const float* __restrict__ B,
                                                 const float* __restrict__ bias,
                                                 float* __restrict__ C,
                                                 unsigned short* __restrict__ Cbf,
                                                 int M, int K, int N){
  __shared__ float As[KT][TS+1];
  __shared__ float Bs[KT][TS+1];
  int t = threadIdx.x;
  int tx = t & 15, ty = t >> 4;
  int bm = blockIdx.y * TS, bn = blockIdx.x * TS;
  float acc[4][4] = {{0.f}};
  for(int k0=0;k0<K;k0+=KT){
    #pragma unroll
    for(int i=t;i<TS*KT;i+=256){
      int m = i >> 4, kk = i & 15;
      As[kk][m] = A[(bm+m)*K + k0 + kk];
      int k2 = i >> 6, nn = i & 63;
      Bs[k2][nn] = B[(k0+k2)*N + bn + nn];
    }
    __syncthreads();
    #pragma unroll
    for(int kk=0;kk<KT;kk++){
      float a[4], b[4];
      #pragma unroll
      for(int i=0;i<4;i++) a[i]=As[kk][ty*4+i];
      #pragma unroll
      for(int j=0;j<4;j++) b[j]=Bs[kk][tx*4+j];
      #pragma unroll
      for(int i=0;i<4;i++)
        #pragma unroll
        for(int j=0;j<4;j++) acc[i][j] += a[i]*b[j];
    }
    __syncthreads();
  }
  #pragma unroll
  for(int i=0;i<4;i++){
    int m = bm + ty*4 + i;
    #pragma unroll
    for(int j=0;j<4;j++){
      int n = bn + tx*4 + j;
      float v = acc[i][j];
      if(bias) v += bias[n];
      if(Cbf) Cbf[m*N+n] = f2bf(v);
      else    C[m*N+n] = v;
    }
  }
}

// --------- per-node attention coefficients: als/ald [N,H] ---------
__global__ __launch_bounds__(256) void attn_coef(const float* __restrict__ xl,
                                                 const float* __restrict__ a_s,
                                                 const float* __restrict__ a_d,
                                                 float* __restrict__ als,
                                                 float* __restrict__ ald,
                                                 int H, int C){
  int n = blockIdx.x, t = threadIdx.x;
  int D = H*C;
  __shared__ float s1[4], s2[4];
  int lane = t & 63, wid = t >> 6;
  for(int h=0;h<H;h++){
    float ps=0.f, pd=0.f;
    for(int c=t;c<C;c+=256){
      float v = xl[n*D + h*C + c];
      ps += v * a_s[h*C+c];
      pd += v * a_d[h*C+c];
    }
    ps = waveReduceSum(ps);
    pd = waveReduceSum(pd);
    if(lane==0){ s1[wid]=ps; s2[wid]=pd; }
    __syncthreads();
    if(t==0){
      float u=0.f,w=0.f;
      #pragma unroll
      for(int i=0;i<4;i++){u+=s1[i]; w+=s2[i];}
      als[n*H+h]=u; ald[n*H+h]=w;
    }
    __syncthreads();
  }
}

// ---------------- CSR build ----------------
__global__ void zero_ints(int* p, int n){
  int i = blockIdx.x*256 + threadIdx.x;
  if(i<n) p[i]=0;
}

__global__ void csr_count(const int* __restrict__ ei, int E, int Etot,
                          int* __restrict__ hist){
  int e = blockIdx.x*256 + threadIdx.x;
  if(e>=Etot) return;
  int d = (e<E) ? (ei[E+e]&4095) : (e-E);
  atomicAdd(&hist[d], 1);
}

// single block, 1024 threads, N=4096
__global__ __launch_bounds__(1024) void csr_scan(const int* __restrict__ hist,
                                                 int* __restrict__ row_ptr,
                                                 int* __restrict__ wcnt, int N){
  __shared__ int sh[1024];
  int t = threadIdx.x;
  int base[4];
  int s = 0;
  #pragma unroll
  for(int i=0;i<4;i++){ base[i]=s; s += hist[t*4+i]; }
  sh[t] = s;
  __syncthreads();
  for(int off=1; off<1024; off<<=1){
    int x = (t>=off) ? sh[t-off] : 0;
    __syncthreads();
    sh[t] += x;
    __syncthreads();
  }
  int excl = (t==0) ? 0 : sh[t-1];
  #pragma unroll
  for(int i=0;i<4;i++){
    row_ptr[t*4+i] = excl + base[i];
    wcnt[t*4+i]    = excl + base[i];
  }
  if(t==1023) row_ptr[N] = excl + s;
}

__global__ void csr_scatter(const int* __restrict__ ei, int E, int Etot,
                            int* __restrict__ wcnt, int* __restrict__ col){
  int e = blockIdx.x*256 + threadIdx.x;
  if(e>=Etot) return;
  int s,d;
  if(e<E){ s=ei[e]&4095; d=ei[E+e]&4095; } else { s=d=e-E; }
  int pos = atomicAdd(&wcnt[d], 1);
  col[pos] = s;
}

// ------- fused GAT gather: softmax (no max, alphas bounded) + aggregate -------
// One block per destination node. No atomics. out = sum(p*x_src)/sum(p).
__global__ __launch_bounds__(256) void gat_gather(const int* __restrict__ rp,
                                                  const int* __restrict__ col,
                                                  const float* __restrict__ xl,
                                                  const float* __restrict__ als,
                                                  const float* __restrict__ ald,
                                                  float* __restrict__ aggr,
                                                  int D, int logC, int H){
  int n = blockIdx.x, t = threadIdx.x;
  int start = rp[n], end = rp[n+1];
  int h0 = t >> logC;
  int h1 = (t + 256) >> logC;
  float ad0 = ald[n*H + h0];
  float ad1 = (D==512) ? ald[n*H + h1] : 0.f;
  float acc0=0.f, acc1=0.f, den0=0.f, den1=0.f;
  for(int j=start;j<end;j++){
    int s = col[j];
    float a0 = als[s*H + h0] + ad0;
    a0 = a0>0.f ? a0 : 0.2f*a0;
    float p0 = __expf(a0);
    acc0 += p0 * xl[s*D + t];
    den0 += p0;
    if(D==512){
      float a1 = als[s*H + h1] + ad1;
      a1 = a1>0.f ? a1 : 0.2f*a1;
      float p1 = __expf(a1);
      acc1 += p1 * xl[s*D + t + 256];
      den1 += p1;
    }
  }
  aggr[n*D + t] = acc0 / (den0 + 1e-16f);
  if(D==512) aggr[n*D + t + 256] = acc1 / (den1 + 1e-16f);
}

// --------- finalize: bias + (ELU) + LayerNorm (+residual) ---------
__global__ __launch_bounds__(256) void finalize_ln(const float* __restrict__ aggr,
                                                   const float* __restrict__ bias,
                                                   const float* __restrict__ g,
                                                   const float* __restrict__ be,
                                                   const float* __restrict__ res,
                                                   float* __restrict__ out,
                                                   int D, int do_elu){
  int n = blockIdx.x, t = threadIdx.x;
  __shared__ float sh[4];
  float v[2];
  int cnt = D >> 8;
  float sum = 0.f;
  for(int i=0;i<cnt;i++){
    int j = t + (i<<8);
    float x = aggr[n*D+j] + bias[j];
    if(do_elu) x = x>0.f ? x : expm1f(x);
    v[i]=x; sum += x;
  }
  sum = waveReduceSum(sum);
  int lane=t&63, wid=t>>6;
  if(lane==0) sh[wid]=sum;
  __syncthreads();
  float mean = (sh[0]+sh[1]+sh[2]+sh[3]) / (float)D;
  __syncthreads();
  float vs=0.f;
  for(int i=0;i<cnt;i++){ float dd=v[i]-mean; vs+=dd*dd; }
  vs = waveReduceSum(vs);
  if(lane==0) sh[wid]=vs;
  __syncthreads();
  float var = (sh[0]+sh[1]+sh[2]+sh[3]) / (float)D;
  float inv = rsqrtf(var + 1e-5f);
  for(int i=0;i<cnt;i++){
    int j = t + (i<<8);
    float y = (v[i]-mean)*inv*g[j] + be[j];
    if(res) y += res[n*D+j];
    out[n*D+j]=y;
  }
}

// --------- MFMA bf16 dense MHA: block = (64-query tile, head) ---------
// Q/K/V pre-converted to bf16. dk=32 == MFMA K exactly.
// A-frag: A[m=lane&15][k=(lane>>4)*8+j]; B-frag: B[k=(lane>>4)*8+j][n=lane&15];
// C/D: col=lane&15, row=(lane>>4)*4+reg.  (verified layouts, m89/m120)
// No running max: scores bounded (LN'ed inputs), exp(s) safe in fp32.
__global__ __launch_bounds__(256) void attention3(const unsigned short* __restrict__ Qh,
                                                  const unsigned short* __restrict__ Kh,
                                                  const unsigned short* __restrict__ Vh,
                                                  float* __restrict__ O, int S){
  const int D = 256;
  int qb = blockIdx.x * 64;
  int h  = blockIdx.y;
  int t  = threadIdx.x;
  int lane = t & 63, w = t >> 6;
  int m = lane & 15, g = lane >> 4;

  __shared__ unsigned short Ps[64*72];  // P, row stride 72 (144B, 16B-mult)
  __shared__ unsigned short Vs[32*72];  // V^T, [dim][key]

  // Q A-fragment: one per wave, reused for all key tiles
  short8 aQ = *(const short8*)(Qh + (qb + w*16 + m)*D + h*32 + g*8);

  const float scale = 0.17677669529663687f; // 1/sqrt(32)
  float4v o0 = {0.f,0.f,0.f,0.f}, o1 = {0.f,0.f,0.f,0.f};
  float l[4] = {0.f,0.f,0.f,0.f};

  int vk = t >> 2;        // 0..63 : key row staged by this thread
  int vd = (t & 3) * 8;   // dim chunk

  for(int kt=0; kt<S; kt+=64){
    __syncthreads();
    // stage V^T (coalesced 16B global read, scattered b16 LDS writes)
    short8 v8 = *(const short8*)(Vh + (kt+vk)*D + h*32 + vd);
    #pragma unroll
    for(int i=0;i<8;i++) Vs[(vd+i)*72 + vk] = (unsigned short)v8[i];

    // S strip (16 q-rows x 64 keys per wave), exp, write P to LDS
    #pragma unroll
    for(int nt=0;nt<4;nt++){
      short8 bK = *(const short8*)(Kh + (kt + nt*16 + m)*D + h*32 + g*8);
      float4v acc = {0.f,0.f,0.f,0.f};
      acc = __builtin_amdgcn_mfma_f32_16x16x32_bf16(aQ, bK, acc, 0,0,0);
      #pragma unroll
      for(int r=0;r<4;r++){
        float p = __expf(acc[r]*scale);
        l[r] += p;
        Ps[(w*16 + g*4 + r)*72 + nt*16 + m] = f2bf(p);
      }
    }
    __syncthreads();

    // O strip += P @ V  (16q x 32d per wave, K=64 in two halves)
    #pragma unroll
    for(int kh=0;kh<2;kh++){
      short8 aP  = *(const short8*)&Ps[(w*16 + m)*72 + kh*32 + g*8];
      short8 bV0 = *(const short8*)&Vs[(m)*72      + kh*32 + g*8];
      short8 bV1 = *(const short8*)&Vs[(16+m)*72   + kh*32 + g*8];
      o0 = __builtin_amdgcn_mfma_f32_16x16x32_bf16(aP, bV0, o0, 0,0,0);
      o1 = __builtin_amdgcn_mfma_f32_16x16x32_bf16(aP, bV1, o1, 0,0,0);
    }
  }

  // row-sum l: reduce over the 16 lanes sharing g (xor over m bits)
  #pragma unroll
  for(int r=0;r<4;r++){
    float li = l[r];
    li += __shfl_xor(li,1,64); li += __shfl_xor(li,2,64);
    li += __shfl_xor(li,4,64); li += __shfl_xor(li,8,64);
    l[r] = 1.f/li;
  }
  #pragma unroll
  for(int r=0;r<4;r++){
    int q = qb + w*16 + g*4 + r;
    O[q*D + h*32 + m]      = o0[r]*l[r];
    O[q*D + h*32 + 16 + m] = o1[r]*l[r];
  }
}

extern "C" void kernel_launch(void* const* d_in, const int* in_sizes, int n_in,
                              void* d_out, int out_size, void* d_ws, size_t ws_size,
                              hipStream_t stream) {
  const float* x   = (const float*)d_in[0];
  const int*   ei  = (const int*)d_in[1];
  const float* W0  = (const float*)d_in[2];
  const float* as0 = (const float*)d_in[3];
  const float* ad0 = (const float*)d_in[4];
  const float* b0  = (const float*)d_in[5];
  const float* W1  = (const float*)d_in[6];
  const float* as1 = (const float*)d_in[7];
  const float* ad1 = (const float*)d_in[8];
  const float* b1  = (const float*)d_in[9];
  const float* W2  = (const float*)d_in[10];
  const float* as2 = (const float*)d_in[11];
  const float* ad2 = (const float*)d_in[12];
  const float* b2  = (const float*)d_in[13];
  const float* g0  = (const float*)d_in[14];
  const float* be0 = (const float*)d_in[15];
  const float* g1  = (const float*)d_in[16];
  const float* be1 = (const float*)d_in[17];
  const float* g2  = (const float*)d_in[18];
  const float* be2 = (const float*)d_in[19];
  const float* wq  = (const float*)d_in[20];
  const float* bq  = (const float*)d_in[21];
  const float* wk  = (const float*)d_in[22];
  const float* bk  = (const float*)d_in[23];
  const float* wv  = (const float*)d_in[24];
  const float* bv  = (const float*)d_in[25];
  const float* wo  = (const float*)d_in[26];
  const float* bo  = (const float*)d_in[27];
  float* out = (float*)d_out;

  const int N = 4096;
  const int E = in_sizes[1] / 2;
  const int Etot = E + N;

  float* ws = (float*)d_ws;
  float* xl   = ws;  ws += N*512;
  float* aggr = ws;  ws += N*512;
  float* h0   = ws;  ws += N*512;
  float* h1   = ws;  ws += N*512;
  float* h2   = ws;  ws += N*256;
  float* ao   = ws;  ws += N*256;
  float* als  = ws;  ws += N*4;
  float* ald  = ws;  ws += N*4;
  unsigned short* Qh = (unsigned short*)ws; ws += N*128;  // bf16 [N,256]
  unsigned short* Kh = (unsigned short*)ws; ws += N*128;
  unsigned short* Vh = (unsigned short*)ws; ws += N*128;
  int* hist = (int*)ws; ws += N/1 * 1;   // N ints -> N floats worth... keep simple:
  int* wcnt = (int*)ws; ws += N;
  int* rp   = (int*)ws; ws += N+2;
  int* col  = (int*)ws; ws += Etot;

  // ---------- CSR build (by destination), once ----------
  zero_ints<<<(N+255)/256, 256, 0, stream>>>(hist, N);
  csr_count<<<(Etot+255)/256, 256, 0, stream>>>(ei, E, Etot, hist);
  csr_scan<<<1, 1024, 0, stream>>>(hist, rp, wcnt, N);
  csr_scatter<<<(Etot+255)/256, 256, 0, stream>>>(ei, E, Etot, wcnt, col);

  // ---------- GAT layer 0: 128 -> 4x128 (512) ----------
  gemm_bias<<<dim3(512/TS, N/TS), 256, 0, stream>>>(x, W0, nullptr, xl, nullptr, N, 128, 512);
  attn_coef<<<N, 256, 0, stream>>>(xl, as0, ad0, als, ald, 4, 128);
  gat_gather<<<N, 256, 0, stream>>>(rp, col, xl, als, ald, aggr, 512, 7, 4);
  finalize_ln<<<N, 256, 0, stream>>>(aggr, b0, g0, be0, nullptr, h0, 512, 1);

  // ---------- GAT layer 1: 512 -> 4x128 (512), residual ----------
  gemm_bias<<<dim3(512/TS, N/TS), 256, 0, stream>>>(h0, W1, nullptr, xl, nullptr, N, 512, 512);
  attn_coef<<<N, 256, 0, stream>>>(xl, as1, ad1, als, ald, 4, 128);
  gat_gather<<<N, 256, 0, stream>>>(rp, col, xl, als, ald, aggr, 512, 7, 4);
  finalize_ln<<<N, 256, 0, stream>>>(aggr, b1, g1, be1, h0, h1, 512, 1);

  // ---------- GAT layer 2: 512 -> 1x256, 1 head, no ELU ----------
  gemm_bias<<<dim3(256/TS, N/TS), 256, 0, stream>>>(h1, W2, nullptr, xl, nullptr, N, 512, 256);
  attn_coef<<<N, 256, 0, stream>>>(xl, as2, ad2, als, ald, 1, 256);
  gat_gather<<<N, 256, 0, stream>>>(rp, col, xl, als, ald, aggr, 256, 8, 1);
  finalize_ln<<<N, 256, 0, stream>>>(aggr, b2, g2, be2, nullptr, h2, 256, 0);

  // ---------- dense MHA over 4096 nodes (bf16 MFMA) ----------
  gemm_bias<<<dim3(256/TS, N/TS), 256, 0, stream>>>(h2, wq, bq, nullptr, Qh, N, 256, 256);
  gemm_bias<<<dim3(256/TS, N/TS), 256, 0, stream>>>(h2, wk, bk, nullptr, Kh, N, 256, 256);
  gemm_bias<<<dim3(256/TS, N/TS), 256, 0, stream>>>(h2, wv, bv, nullptr, Vh, N, 256, 256);
  attention3<<<dim3(N/64, 8), 256, 0, stream>>>(Qh, Kh, Vh, ao, N);
  gemm_bias<<<dim3(256/TS, N/TS), 256, 0, stream>>>(ao, wo, bo, out, nullptr, N, 256, 256);
}

// Round 4
// 587.147 us; speedup vs baseline: 6.7192x; 1.2454x over previous
//
#include <hip/hip_runtime.h>
#include <math.h>

typedef __attribute__((ext_vector_type(8))) short short8;
typedef __attribute__((ext_vector_type(4))) float float4v;

__device__ __forceinline__ float waveReduceSum(float v){
  #pragma unroll
  for(int o=32;o>0;o>>=1) v += __shfl_down(v,o,64);
  return v;
}

__device__ __forceinline__ unsigned short f2bf(float f){
  unsigned int u = __float_as_uint(f);
  return (unsigned short)((u + 0x7FFFu + ((u>>16)&1u)) >> 16);
}

// ---------------- one-time converts ----------------
__global__ void conv_bf16(const float* __restrict__ X, unsigned short* __restrict__ Xb, int n){
  int i = blockIdx.x*256 + threadIdx.x;
  if(i<n) Xb[i] = f2bf(X[i]);
}

// W[K][N] fp32 -> Wt[N][K] bf16
__global__ void transpose_bf16(const float* __restrict__ W, unsigned short* __restrict__ Wt,
                               int K, int N){
  int idx = blockIdx.x*256 + threadIdx.x;
  if(idx >= K*N) return;
  int k = idx / N, n = idx - k*N;
  Wt[n*K + k] = f2bf(W[idx]);
}

// ---------------- MFMA bf16 GEMM, zero-LDS ----------------
// A bf16 [M,K] row-major; Bt bf16 [N,K] row-major (B transposed).
// Outputs (any subset non-null): C fp32 [M,N], Cb bf16 [M,N], Ct bf16 [N,M].
// A-frag: A[m=lane&15][k=g*8+j]; B-frag: B[k=g*8+j][n=lane&15] = Bt[n][k];
// C/D: col=lane&15, row=g*4+reg. (verified layouts)
__global__ __launch_bounds__(256) void gemm_mfma(const unsigned short* __restrict__ A,
                                                 const unsigned short* __restrict__ Bt,
                                                 const float* __restrict__ bias,
                                                 float* __restrict__ C,
                                                 unsigned short* __restrict__ Cb,
                                                 unsigned short* __restrict__ Ct,
                                                 int M, int K, int N){
  int t = threadIdx.x, lane = t & 63, w = t >> 6;
  int m = lane & 15, g = lane >> 4;
  int bm = blockIdx.y * 64, bn = blockIdx.x * 64;

  const unsigned short* Ap = A + (bm + w*16 + m)*K + g*8;
  const unsigned short* Bp = Bt + (bn + m)*K + g*8;

  float4v acc[4];
  #pragma unroll
  for(int nt=0;nt<4;nt++) acc[nt] = (float4v){0.f,0.f,0.f,0.f};

  for(int k0=0;k0<K;k0+=32){
    short8 aA = *(const short8*)(Ap + k0);
    #pragma unroll
    for(int nt=0;nt<4;nt++){
      short8 bB = *(const short8*)(Bp + nt*16*K + k0);
      acc[nt] = __builtin_amdgcn_mfma_f32_16x16x32_bf16(aA, bB, acc[nt], 0,0,0);
    }
  }
  #pragma unroll
  for(int nt=0;nt<4;nt++){
    int col = bn + nt*16 + m;
    float bv = bias ? bias[col] : 0.f;
    #pragma unroll
    for(int r=0;r<4;r++){
      int row = bm + w*16 + g*4 + r;
      float v = acc[nt][r] + bv;
      if(C)  C[row*N + col]  = v;
      if(Cb) Cb[row*N + col] = f2bf(v);
      if(Ct) Ct[col*M + row] = f2bf(v);
    }
  }
}

// --------- per-node attention coefficients: als/ald [N,H] ---------
__global__ __launch_bounds__(256) void attn_coef(const float* __restrict__ xl,
                                                 const float* __restrict__ a_s,
                                                 const float* __restrict__ a_d,
                                                 float* __restrict__ als,
                                                 float* __restrict__ ald,
                                                 int H, int C){
  int n = blockIdx.x, t = threadIdx.x;
  int D = H*C;
  __shared__ float s1[4], s2[4];
  int lane = t & 63, wid = t >> 6;
  for(int h=0;h<H;h++){
    float ps=0.f, pd=0.f;
    for(int c=t;c<C;c+=256){
      float v = xl[n*D + h*C + c];
      ps += v * a_s[h*C+c];
      pd += v * a_d[h*C+c];
    }
    ps = waveReduceSum(ps);
    pd = waveReduceSum(pd);
    if(lane==0){ s1[wid]=ps; s2[wid]=pd; }
    __syncthreads();
    if(t==0){
      float u=0.f,w=0.f;
      #pragma unroll
      for(int i=0;i<4;i++){u+=s1[i]; w+=s2[i];}
      als[n*H+h]=u; ald[n*H+h]=w;
    }
    __syncthreads();
  }
}

// ---------------- CSR build ----------------
__global__ void zero_ints(int* p, int n){
  int i = blockIdx.x*256 + threadIdx.x;
  if(i<n) p[i]=0;
}

__global__ void csr_count(const int* __restrict__ ei, int E, int Etot,
                          int* __restrict__ hist){
  int e = blockIdx.x*256 + threadIdx.x;
  if(e>=Etot) return;
  int d = (e<E) ? (ei[E+e]&4095) : (e-E);
  atomicAdd(&hist[d], 1);
}

__global__ __launch_bounds__(1024) void csr_scan(const int* __restrict__ hist,
                                                 int* __restrict__ row_ptr,
                                                 int* __restrict__ wcnt, int N){
  __shared__ int sh[1024];
  int t = threadIdx.x;
  int base[4];
  int s = 0;
  #pragma unroll
  for(int i=0;i<4;i++){ base[i]=s; s += hist[t*4+i]; }
  sh[t] = s;
  __syncthreads();
  for(int off=1; off<1024; off<<=1){
    int x = (t>=off) ? sh[t-off] : 0;
    __syncthreads();
    sh[t] += x;
    __syncthreads();
  }
  int excl = (t==0) ? 0 : sh[t-1];
  #pragma unroll
  for(int i=0;i<4;i++){
    row_ptr[t*4+i] = excl + base[i];
    wcnt[t*4+i]    = excl + base[i];
  }
  if(t==1023) row_ptr[N] = excl + s;
}

__global__ void csr_scatter(const int* __restrict__ ei, int E, int Etot,
                            int* __restrict__ wcnt, int* __restrict__ col){
  int e = blockIdx.x*256 + threadIdx.x;
  if(e>=Etot) return;
  int s,d;
  if(e<E){ s=ei[e]&4095; d=ei[E+e]&4095; } else { s=d=e-E; }
  int pos = atomicAdd(&wcnt[d], 1);
  col[pos] = s;
}

// ------- fused GAT gather: softmax (no max, alphas bounded) + aggregate -------
__global__ __launch_bounds__(256) void gat_gather(const int* __restrict__ rp,
                                                  const int* __restrict__ col,
                                                  const float* __restrict__ xl,
                                                  const float* __restrict__ als,
                                                  const float* __restrict__ ald,
                                                  float* __restrict__ aggr,
                                                  int D, int logC, int H){
  int n = blockIdx.x, t = threadIdx.x;
  int start = rp[n], end = rp[n+1];
  int h0 = t >> logC;
  int h1 = (t + 256) >> logC;
  float ad0 = ald[n*H + h0];
  float ad1 = (D==512) ? ald[n*H + h1] : 0.f;
  float acc0=0.f, acc1=0.f, den0=0.f, den1=0.f;
  for(int j=start;j<end;j++){
    int s = col[j];
    float a0 = als[s*H + h0] + ad0;
    a0 = a0>0.f ? a0 : 0.2f*a0;
    float p0 = __expf(a0);
    acc0 += p0 * xl[s*D + t];
    den0 += p0;
    if(D==512){
      float a1 = als[s*H + h1] + ad1;
      a1 = a1>0.f ? a1 : 0.2f*a1;
      float p1 = __expf(a1);
      acc1 += p1 * xl[s*D + t + 256];
      den1 += p1;
    }
  }
  aggr[n*D + t] = acc0 / (den0 + 1e-16f);
  if(D==512) aggr[n*D + t + 256] = acc1 / (den1 + 1e-16f);
}

// --------- finalize: bias + (ELU) + LayerNorm (+residual), fp32/bf16 outs ---------
__global__ __launch_bounds__(256) void finalize_ln(const float* __restrict__ aggr,
                                                   const float* __restrict__ bias,
                                                   const float* __restrict__ g,
                                                   const float* __restrict__ be,
                                                   const float* __restrict__ res,
                                                   float* __restrict__ out,
                                                   unsigned short* __restrict__ outb,
                                                   int D, int do_elu){
  int n = blockIdx.x, t = threadIdx.x;
  __shared__ float sh[4];
  float v[2];
  int cnt = D >> 8;
  float sum = 0.f;
  for(int i=0;i<cnt;i++){
    int j = t + (i<<8);
    float x = aggr[n*D+j] + bias[j];
    if(do_elu) x = x>0.f ? x : expm1f(x);
    v[i]=x; sum += x;
  }
  sum = waveReduceSum(sum);
  int lane=t&63, wid=t>>6;
  if(lane==0) sh[wid]=sum;
  __syncthreads();
  float mean = (sh[0]+sh[1]+sh[2]+sh[3]) / (float)D;
  __syncthreads();
  float vs=0.f;
  for(int i=0;i<cnt;i++){ float dd=v[i]-mean; vs+=dd*dd; }
  vs = waveReduceSum(vs);
  if(lane==0) sh[wid]=vs;
  __syncthreads();
  float var = (sh[0]+sh[1]+sh[2]+sh[3]) / (float)D;
  float inv = rsqrtf(var + 1e-5f);
  for(int i=0;i<cnt;i++){
    int j = t + (i<<8);
    float y = (v[i]-mean)*inv*g[j] + be[j];
    if(res) y += res[n*D+j];
    if(out)  out[n*D+j]  = y;
    if(outb) outb[n*D+j] = f2bf(y);
  }
}

// --------- MFMA bf16 dense MHA v2: V pre-transposed, no V staging ---------
// Vt bf16 [256][S]. Only P round-trips through LDS. Output bf16.
__global__ __launch_bounds__(256) void attention4(const unsigned short* __restrict__ Qh,
                                                  const unsigned short* __restrict__ Kh,
                                                  const unsigned short* __restrict__ Vt,
                                                  unsigned short* __restrict__ Ob, int S){
  const int D = 256;
  int qb = blockIdx.x * 64;
  int h  = blockIdx.y;
  int t  = threadIdx.x;
  int lane = t & 63, w = t >> 6;
  int m = lane & 15, g = lane >> 4;

  __shared__ unsigned short Ps[64*72];  // row stride 72 (144B, 16B-mult)

  short8 aQ = *(const short8*)(Qh + (qb + w*16 + m)*D + h*32 + g*8);

  const float scale = 0.17677669529663687f; // 1/sqrt(32)
  float4v o0 = {0.f,0.f,0.f,0.f}, o1 = {0.f,0.f,0.f,0.f};
  float l[4] = {0.f,0.f,0.f,0.f};

  const unsigned short* V0 = Vt + (h*32 + m)*S;
  const unsigned short* V1 = Vt + (h*32 + 16 + m)*S;

  for(int kt=0; kt<S; kt+=64){
    // S strip (16 q-rows x 64 keys per wave), exp, write P to LDS
    #pragma unroll
    for(int nt=0;nt<4;nt++){
      short8 bK = *(const short8*)(Kh + (kt + nt*16 + m)*D + h*32 + g*8);
      float4v acc = {0.f,0.f,0.f,0.f};
      acc = __builtin_amdgcn_mfma_f32_16x16x32_bf16(aQ, bK, acc, 0,0,0);
      #pragma unroll
      for(int r=0;r<4;r++){
        float p = __expf(acc[r]*scale);
        l[r] += p;
        Ps[(w*16 + g*4 + r)*72 + nt*16 + m] = f2bf(p);
      }
    }
    __syncthreads();

    // O strip += P @ V  (16q x 32d per wave), V B-frags direct from global
    #pragma unroll
    for(int kh=0;kh<2;kh++){
      short8 aP  = *(const short8*)&Ps[(w*16 + m)*72 + kh*32 + g*8];
      short8 bV0 = *(const short8*)(V0 + kt + kh*32 + g*8);
      short8 bV1 = *(const short8*)(V1 + kt + kh*32 + g*8);
      o0 = __builtin_amdgcn_mfma_f32_16x16x32_bf16(aP, bV0, o0, 0,0,0);
      o1 = __builtin_amdgcn_mfma_f32_16x16x32_bf16(aP, bV1, o1, 0,0,0);
    }
    __syncthreads();
  }

  #pragma unroll
  for(int r=0;r<4;r++){
    float li = l[r];
    li += __shfl_xor(li,1,64); li += __shfl_xor(li,2,64);
    li += __shfl_xor(li,4,64); li += __shfl_xor(li,8,64);
    l[r] = 1.f/li;
  }
  #pragma unroll
  for(int r=0;r<4;r++){
    int q = qb + w*16 + g*4 + r;
    Ob[q*D + h*32 + m]      = f2bf(o0[r]*l[r]);
    Ob[q*D + h*32 + 16 + m] = f2bf(o1[r]*l[r]);
  }
}

extern "C" void kernel_launch(void* const* d_in, const int* in_sizes, int n_in,
                              void* d_out, int out_size, void* d_ws, size_t ws_size,
                              hipStream_t stream) {
  const float* x   = (const float*)d_in[0];
  const int*   ei  = (const int*)d_in[1];
  const float* W0  = (const float*)d_in[2];
  const float* as0 = (const float*)d_in[3];
  const float* ad0 = (const float*)d_in[4];
  const float* b0  = (const float*)d_in[5];
  const float* W1  = (const float*)d_in[6];
  const float* as1 = (const float*)d_in[7];
  const float* ad1 = (const float*)d_in[8];
  const float* b1  = (const float*)d_in[9];
  const float* W2  = (const float*)d_in[10];
  const float* as2 = (const float*)d_in[11];
  const float* ad2 = (const float*)d_in[12];
  const float* b2  = (const float*)d_in[13];
  const float* g0  = (const float*)d_in[14];
  const float* be0 = (const float*)d_in[15];
  const float* g1  = (const float*)d_in[16];
  const float* be1 = (const float*)d_in[17];
  const float* g2  = (const float*)d_in[18];
  const float* be2 = (const float*)d_in[19];
  const float* wq  = (const float*)d_in[20];
  const float* bq  = (const float*)d_in[21];
  const float* wk  = (const float*)d_in[22];
  const float* bk  = (const float*)d_in[23];
  const float* wv  = (const float*)d_in[24];
  const float* bv  = (const float*)d_in[25];
  const float* wo  = (const float*)d_in[26];
  const float* bo  = (const float*)d_in[27];
  float* out = (float*)d_out;

  const int N = 4096;
  const int E = in_sizes[1] / 2;
  const int Etot = E + N;

  char* p = (char*)d_ws;
  auto alloc = [&](size_t bytes){ char* r = p; p += (bytes + 255) & ~(size_t)255; return r; };

  float* xl   = (float*)alloc(N*512*4);
  float* aggr = (float*)alloc(N*512*4);
  float* h0   = (float*)alloc(N*512*4);
  float* als  = (float*)alloc(N*4*4);
  float* ald  = (float*)alloc(N*4*4);
  unsigned short* xb  = (unsigned short*)alloc(N*128*2);
  unsigned short* h0b = (unsigned short*)alloc(N*512*2);
  unsigned short* h1b = (unsigned short*)alloc(N*512*2);
  unsigned short* h2b = (unsigned short*)alloc(N*256*2);
  unsigned short* Qh  = (unsigned short*)alloc(N*256*2);
  unsigned short* Kh  = (unsigned short*)alloc(N*256*2);
  unsigned short* Vt  = (unsigned short*)alloc(256*N*2);
  unsigned short* aob = (unsigned short*)alloc(N*256*2);
  unsigned short* W0t = (unsigned short*)alloc(512*128*2);
  unsigned short* W1t = (unsigned short*)alloc(512*512*2);
  unsigned short* W2t = (unsigned short*)alloc(256*512*2);
  unsigned short* wqt = (unsigned short*)alloc(256*256*2);
  unsigned short* wkt = (unsigned short*)alloc(256*256*2);
  unsigned short* wvt = (unsigned short*)alloc(256*256*2);
  unsigned short* wot = (unsigned short*)alloc(256*256*2);
  int* hist = (int*)alloc(N*4);
  int* wcnt = (int*)alloc(N*4);
  int* rp   = (int*)alloc((N+2)*4);
  int* col  = (int*)alloc(Etot*4);

  // ---------- one-time converts ----------
  conv_bf16<<<(N*128+255)/256, 256, 0, stream>>>(x, xb, N*128);
  transpose_bf16<<<(128*512+255)/256, 256, 0, stream>>>(W0, W0t, 128, 512);
  transpose_bf16<<<(512*512+255)/256, 256, 0, stream>>>(W1, W1t, 512, 512);
  transpose_bf16<<<(512*256+255)/256, 256, 0, stream>>>(W2, W2t, 512, 256);
  transpose_bf16<<<(256*256+255)/256, 256, 0, stream>>>(wq, wqt, 256, 256);
  transpose_bf16<<<(256*256+255)/256, 256, 0, stream>>>(wk, wkt, 256, 256);
  transpose_bf16<<<(256*256+255)/256, 256, 0, stream>>>(wv, wvt, 256, 256);
  transpose_bf16<<<(256*256+255)/256, 256, 0, stream>>>(wo, wot, 256, 256);

  // ---------- CSR build (by destination) ----------
  zero_ints<<<(N+255)/256, 256, 0, stream>>>(hist, N);
  csr_count<<<(Etot+255)/256, 256, 0, stream>>>(ei, E, Etot, hist);
  csr_scan<<<1, 1024, 0, stream>>>(hist, rp, wcnt, N);
  csr_scatter<<<(Etot+255)/256, 256, 0, stream>>>(ei, E, Etot, wcnt, col);

  // ---------- GAT layer 0: 128 -> 4x128 (512) ----------
  gemm_mfma<<<dim3(512/64, N/64), 256, 0, stream>>>(xb, W0t, nullptr, xl, nullptr, nullptr, N, 128, 512);
  attn_coef<<<N, 256, 0, stream>>>(xl, as0, ad0, als, ald, 4, 128);
  gat_gather<<<N, 256, 0, stream>>>(rp, col, xl, als, ald, aggr, 512, 7, 4);
  finalize_ln<<<N, 256, 0, stream>>>(aggr, b0, g0, be0, nullptr, h0, h0b, 512, 1);

  // ---------- GAT layer 1: 512 -> 4x128 (512), residual ----------
  gemm_mfma<<<dim3(512/64, N/64), 256, 0, stream>>>(h0b, W1t, nullptr, xl, nullptr, nullptr, N, 512, 512);
  attn_coef<<<N, 256, 0, stream>>>(xl, as1, ad1, als, ald, 4, 128);
  gat_gather<<<N, 256, 0, stream>>>(rp, col, xl, als, ald, aggr, 512, 7, 4);
  finalize_ln<<<N, 256, 0, stream>>>(aggr, b1, g1, be1, h0, nullptr, h1b, 512, 1);

  // ---------- GAT layer 2: 512 -> 1x256, 1 head, no ELU ----------
  gemm_mfma<<<dim3(256/64, N/64), 256, 0, stream>>>(h1b, W2t, nullptr, xl, nullptr, nullptr, N, 512, 256);
  attn_coef<<<N, 256, 0, stream>>>(xl, as2, ad2, als, ald, 1, 256);
  gat_gather<<<N, 256, 0, stream>>>(rp, col, xl, als, ald, aggr, 256, 8, 1);
  finalize_ln<<<N, 256, 0, stream>>>(aggr, b2, g2, be2, nullptr, nullptr, h2b, 256, 0);

  // ---------- dense MHA over 4096 nodes (bf16 MFMA) ----------
  gemm_mfma<<<dim3(256/64, N/64), 256, 0, stream>>>(h2b, wqt, bq, nullptr, Qh, nullptr, N, 256, 256);
  gemm_mfma<<<dim3(256/64, N/64), 256, 0, stream>>>(h2b, wkt, bk, nullptr, Kh, nullptr, N, 256, 256);
  gemm_mfma<<<dim3(256/64, N/64), 256, 0, stream>>>(h2b, wvt, bv, nullptr, nullptr, Vt, N, 256, 256);
  attention4<<<dim3(N/64, 8), 256, 0, stream>>>(Qh, Kh, Vt, aob, N);
  gemm_mfma<<<dim3(256/64, N/64), 256, 0, stream>>>(aob, wot, bo, out, nullptr, nullptr, N, 256, 256);
}

// Round 5
// 454.810 us; speedup vs baseline: 8.6742x; 1.2910x over previous
//
#include <hip/hip_runtime.h>
#include <math.h>

typedef __attribute__((ext_vector_type(8))) short short8;
typedef __attribute__((ext_vector_type(4))) float float4v;

__device__ __forceinline__ float waveReduceSum(float v){
  #pragma unroll
  for(int o=32;o>0;o>>=1) v += __shfl_down(v,o,64);
  return v;
}

__device__ __forceinline__ unsigned short f2bf(float f){
  unsigned int u = __float_as_uint(f);
  return (unsigned short)((u + 0x7FFFu + ((u>>16)&1u)) >> 16);
}
__device__ __forceinline__ float bf2f(unsigned short u){
  return __uint_as_float(((unsigned int)u)<<16);
}

// ---------------- fused prep: x->bf16 + 7 weight transposes ----------------
// segments (blocks of 256 elems): [0,2048) x-conv 524288; [2048,2304) W0 128x512;
// [2304,3328) W1 512x512; [3328,3840) W2 512x256; [3840,4096) wq; [4096,4352) wk;
// [4352,4608) wv; [4608,4864) wo  (all wq.. 256x256)
__global__ __launch_bounds__(256) void prep(const float* __restrict__ x, unsigned short* __restrict__ xb,
                     const float* __restrict__ W0, unsigned short* __restrict__ W0t,
                     const float* __restrict__ W1, unsigned short* __restrict__ W1t,
                     const float* __restrict__ W2, unsigned short* __restrict__ W2t,
                     const float* __restrict__ wq, unsigned short* __restrict__ wqt,
                     const float* __restrict__ wk, unsigned short* __restrict__ wkt,
                     const float* __restrict__ wv, unsigned short* __restrict__ wvt,
                     const float* __restrict__ wo, unsigned short* __restrict__ wot){
  int b = blockIdx.x, t = threadIdx.x;
  if(b < 2048){ int i = b*256 + t; xb[i] = f2bf(x[i]); return; }
  const float* src; unsigned short* dst; int K,N,base;
  if(b<2304){src=W0;dst=W0t;K=128;N=512;base=2048;}
  else if(b<3328){src=W1;dst=W1t;K=512;N=512;base=2304;}
  else if(b<3840){src=W2;dst=W2t;K=512;N=256;base=3328;}
  else if(b<4096){src=wq;dst=wqt;K=256;N=256;base=3840;}
  else if(b<4352){src=wk;dst=wkt;K=256;N=256;base=4096;}
  else if(b<4608){src=wv;dst=wvt;K=256;N=256;base=4352;}
  else            {src=wo;dst=wot;K=256;N=256;base=4608;}
  int idx = (b-base)*256 + t;
  int k = idx / N, n = idx - k*N;
  dst[n*K + k] = f2bf(src[idx]);
}

// ---------------- MFMA bf16 GEMM, zero-LDS ----------------
// A bf16 [M,K]; Bt bf16 [N,K]. Outputs: C fp32 [M,N] and/or Cb bf16 [M,N].
__global__ __launch_bounds__(256) void gemm_mfma(const unsigned short* __restrict__ A,
                                                 const unsigned short* __restrict__ Bt,
                                                 const float* __restrict__ bias,
                                                 float* __restrict__ C,
                                                 unsigned short* __restrict__ Cb,
                                                 int M, int K, int N){
  int t = threadIdx.x, lane = t & 63, w = t >> 6;
  int m = lane & 15, g = lane >> 4;
  int bm = blockIdx.y * 64, bn = blockIdx.x * 64;

  const unsigned short* Ap = A + (bm + w*16 + m)*K + g*8;
  const unsigned short* Bp = Bt + (bn + m)*K + g*8;

  float4v acc[4];
  #pragma unroll
  for(int nt=0;nt<4;nt++) acc[nt] = (float4v){0.f,0.f,0.f,0.f};

  for(int k0=0;k0<K;k0+=32){
    short8 aA = *(const short8*)(Ap + k0);
    #pragma unroll
    for(int nt=0;nt<4;nt++){
      short8 bB = *(const short8*)(Bp + nt*16*K + k0);
      acc[nt] = __builtin_amdgcn_mfma_f32_16x16x32_bf16(aA, bB, acc[nt], 0,0,0);
    }
  }
  #pragma unroll
  for(int nt=0;nt<4;nt++){
    int col = bn + nt*16 + m;
    float bv = bias ? bias[col] : 0.f;
    #pragma unroll
    for(int r=0;r<4;r++){
      int row = bm + w*16 + g*4 + r;
      float v = acc[nt][r] + bv;
      if(C)  C[row*N + col]  = v;
      if(Cb) Cb[row*N + col] = f2bf(v);
    }
  }
}

// --------- per-node attention coefficients: als/ald [N,H] (fp32 exact) ---------
__global__ __launch_bounds__(256) void attn_coef(const float* __restrict__ xl,
                                                 const float* __restrict__ a_s,
                                                 const float* __restrict__ a_d,
                                                 float* __restrict__ als,
                                                 float* __restrict__ ald,
                                                 int H, int C){
  int n = blockIdx.x, t = threadIdx.x;
  int D = H*C;
  __shared__ float s1[4], s2[4];
  int lane = t & 63, wid = t >> 6;
  for(int h=0;h<H;h++){
    float ps=0.f, pd=0.f;
    for(int c=t;c<C;c+=256){
      float v = xl[n*D + h*C + c];
      ps += v * a_s[h*C+c];
      pd += v * a_d[h*C+c];
    }
    ps = waveReduceSum(ps);
    pd = waveReduceSum(pd);
    if(lane==0){ s1[wid]=ps; s2[wid]=pd; }
    __syncthreads();
    if(t==0){
      float u=0.f,w=0.f;
      #pragma unroll
      for(int i=0;i<4;i++){u+=s1[i]; w+=s2[i];}
      als[n*H+h]=u; ald[n*H+h]=w;
    }
    __syncthreads();
  }
}

// ---------------- CSR build ----------------
__global__ void zero_ints(int* p, int n){
  int i = blockIdx.x*256 + threadIdx.x;
  if(i<n) p[i]=0;
}

__global__ void csr_count(const int* __restrict__ ei, int E, int Etot,
                          int* __restrict__ hist){
  int e = blockIdx.x*256 + threadIdx.x;
  if(e>=Etot) return;
  int d = (e<E) ? (ei[E+e]&4095) : (e-E);
  atomicAdd(&hist[d], 1);
}

__global__ __launch_bounds__(1024) void csr_scan(const int* __restrict__ hist,
                                                 int* __restrict__ row_ptr,
                                                 int* __restrict__ wcnt, int N){
  __shared__ int sh[1024];
  int t = threadIdx.x;
  int base[4];
  int s = 0;
  #pragma unroll
  for(int i=0;i<4;i++){ base[i]=s; s += hist[t*4+i]; }
  sh[t] = s;
  __syncthreads();
  for(int off=1; off<1024; off<<=1){
    int x = (t>=off) ? sh[t-off] : 0;
    __syncthreads();
    sh[t] += x;
    __syncthreads();
  }
  int excl = (t==0) ? 0 : sh[t-1];
  #pragma unroll
  for(int i=0;i<4;i++){
    row_ptr[t*4+i] = excl + base[i];
    wcnt[t*4+i]    = excl + base[i];
  }
  if(t==1023) row_ptr[N] = excl + s;
}

__global__ void csr_scatter(const int* __restrict__ ei, int E, int Etot,
                            int* __restrict__ wcnt, int* __restrict__ col){
  int e = blockIdx.x*256 + threadIdx.x;
  if(e>=Etot) return;
  int s,d;
  if(e<E){ s=ei[e]&4095; d=ei[E+e]&4095; } else { s=d=e-E; }
  int pos = atomicAdd(&wcnt[d], 1);
  col[pos] = s;
}

// ------- fused GAT gather + softmax + bias + ELU + LayerNorm (+residual) -------
// One block per destination node; reads bf16 features; no atomics.
__global__ __launch_bounds__(256) void gat_gather_ln(const int* __restrict__ rp,
                                                     const int* __restrict__ col,
                                                     const unsigned short* __restrict__ xlb,
                                                     const float* __restrict__ als,
                                                     const float* __restrict__ ald,
                                                     const float* __restrict__ bias,
                                                     const float* __restrict__ gw,
                                                     const float* __restrict__ be,
                                                     const float* __restrict__ res,
                                                     float* __restrict__ out,
                                                     unsigned short* __restrict__ outb,
                                                     int D, int logC, int H, int do_elu){
  int n = blockIdx.x, t = threadIdx.x;
  int start = rp[n], end = rp[n+1];
  int h0 = t >> logC;
  int h1 = (t + 256) >> logC;
  float ad0 = ald[n*H + h0];
  float ad1 = (D==512) ? ald[n*H + h1] : 0.f;
  float acc0=0.f, acc1=0.f, den0=0.f, den1=0.f;
  for(int j=start;j<end;j++){
    int s = col[j];
    float a0 = als[s*H + h0] + ad0;
    a0 = a0>0.f ? a0 : 0.2f*a0;
    float p0 = __expf(a0);
    acc0 += p0 * bf2f(xlb[s*D + t]);
    den0 += p0;
    if(D==512){
      float a1 = als[s*H + h1] + ad1;
      a1 = a1>0.f ? a1 : 0.2f*a1;
      float p1 = __expf(a1);
      acc1 += p1 * bf2f(xlb[s*D + t + 256]);
      den1 += p1;
    }
  }
  // bias + ELU
  __shared__ float sh[4];
  float v[2];
  int cnt = D >> 8;
  v[0] = acc0/(den0 + 1e-16f) + bias[t];
  if(do_elu) v[0] = v[0]>0.f ? v[0] : expm1f(v[0]);
  float sum = v[0];
  if(cnt==2){
    v[1] = acc1/(den1 + 1e-16f) + bias[t+256];
    if(do_elu) v[1] = v[1]>0.f ? v[1] : expm1f(v[1]);
    sum += v[1];
  }
  sum = waveReduceSum(sum);
  int lane=t&63, wid=t>>6;
  if(lane==0) sh[wid]=sum;
  __syncthreads();
  float mean = (sh[0]+sh[1]+sh[2]+sh[3]) / (float)D;
  __syncthreads();
  float vs=0.f;
  for(int i=0;i<cnt;i++){ float dd=v[i]-mean; vs+=dd*dd; }
  vs = waveReduceSum(vs);
  if(lane==0) sh[wid]=vs;
  __syncthreads();
  float var = (sh[0]+sh[1]+sh[2]+sh[3]) / (float)D;
  float inv = rsqrtf(var + 1e-5f);
  for(int i=0;i<cnt;i++){
    int j = t + (i<<8);
    float y = (v[i]-mean)*inv*gw[j] + be[j];
    if(res) y += res[n*D+j];
    if(out)  out[n*D+j]  = y;
    if(outb) outb[n*D+j] = f2bf(y);
  }
}

// --------- V transpose: Vh bf16 [S,256] -> Vt bf16 [256,S], LDS-tiled ---------
__global__ __launch_bounds__(256) void transpose_v(const unsigned short* __restrict__ Vh,
                                                   unsigned short* __restrict__ Vt, int S){
  __shared__ unsigned short tile[64][72];
  int bs = blockIdx.x*64;   // key block
  int bd = blockIdx.y*64;   // dim block
  int t = threadIdx.x;
  int r8 = t>>3, c8 = (t&7)*8;
  #pragma unroll
  for(int it=0; it<2; it++){
    int row = r8 + it*32;
    short8 v = *(const short8*)(Vh + (bs+row)*256 + bd + c8);
    *(short8*)&tile[row][c8] = v;
  }
  __syncthreads();
  #pragma unroll
  for(int it=0; it<2; it++){
    int drow = r8 + it*32;
    short8 o;
    #pragma unroll
    for(int j=0;j<8;j++) o[j] = (short)tile[c8+j][drow];
    *(short8*)(Vt + (bd+drow)*S + bs + c8) = o;
  }
}

// --------- MFMA bf16 MHA, flash-decode: block=(64q, head, ksplit) ---------
// Partial O (no divide) and partial l written to scratch; combine divides.
// No running max needed: LN-bounded scores, exp safe in fp32; partial sums exact.
#define KS 4
__global__ __launch_bounds__(256) void attention5(const unsigned short* __restrict__ Qh,
                                                  const unsigned short* __restrict__ Kh,
                                                  const unsigned short* __restrict__ Vt,
                                                  float* __restrict__ Op,
                                                  float* __restrict__ lp, int S){
  const int D = 256;
  int qb = blockIdx.x * 64;
  int h  = blockIdx.y;
  int ks = blockIdx.z;
  int t  = threadIdx.x;
  int lane = t & 63, w = t >> 6;
  int m = lane & 15, g = lane >> 4;

  __shared__ unsigned short Ps[64*72];   // [q][key], stride 72
  __shared__ unsigned short Vs[32*72];   // [dim][key], stride 72

  short8 aQ = *(const short8*)(Qh + (qb + w*16 + m)*D + h*32 + g*8);

  const float scale = 0.17677669529663687f; // 1/sqrt(32)
  float4v o0 = {0.f,0.f,0.f,0.f}, o1 = {0.f,0.f,0.f,0.f};
  float l[4] = {0.f,0.f,0.f,0.f};

  int r8 = t>>3, c8 = (t&7)*8;   // staging: dim row, key chunk
  int kA = ks*(S/KS), kB = kA + S/KS;

  for(int kt=kA; kt<kB; kt+=64){
    // stage V^T tile: coalesced b128 read from Vt, b128 write to LDS (balanced banks)
    short8 v = *(const short8*)(Vt + (h*32 + r8)*S + kt + c8);
    *(short8*)&Vs[r8*72 + c8] = v;
    __syncthreads();

    // S strip (16 q x 64 k per wave) -> exp -> P (wave-private rows, no barrier)
    #pragma unroll
    for(int nt=0;nt<4;nt++){
      short8 bK = *(const short8*)(Kh + (kt + nt*16 + m)*D + h*32 + g*8);
      float4v acc = {0.f,0.f,0.f,0.f};
      acc = __builtin_amdgcn_mfma_f32_16x16x32_bf16(aQ, bK, acc, 0,0,0);
      #pragma unroll
      for(int r=0;r<4;r++){
        float p = __expf(acc[r]*scale);
        l[r] += p;
        Ps[(w*16 + g*4 + r)*72 + nt*16 + m] = f2bf(p);
      }
    }

    // O strip += P @ V
    #pragma unroll
    for(int kh=0;kh<2;kh++){
      short8 aP  = *(const short8*)&Ps[(w*16 + m)*72 + kh*32 + g*8];
      short8 bV0 = *(const short8*)&Vs[(m)*72    + kh*32 + g*8];
      short8 bV1 = *(const short8*)&Vs[(16+m)*72 + kh*32 + g*8];
      o0 = __builtin_amdgcn_mfma_f32_16x16x32_bf16(aP, bV0, o0, 0,0,0);
      o1 = __builtin_amdgcn_mfma_f32_16x16x32_bf16(aP, bV1, o1, 0,0,0);
    }
    __syncthreads();
  }

  // reduce l over the 16 m-lanes
  #pragma unroll
  for(int r=0;r<4;r++){
    float li = l[r];
    li += __shfl_xor(li,1,64); li += __shfl_xor(li,2,64);
    li += __shfl_xor(li,4,64); li += __shfl_xor(li,8,64);
    l[r] = li;
  }
  float* Ob = Op + (size_t)ks*S*256;
  #pragma unroll
  for(int r=0;r<4;r++){
    int q = qb + w*16 + g*4 + r;
    Ob[q*256 + h*32 + m]      = o0[r];
    Ob[q*256 + h*32 + 16 + m] = o1[r];
    if(m==0) lp[ks*S*8 + q*8 + h] = l[r];
  }
}

__global__ __launch_bounds__(256) void combine(const float* __restrict__ Op,
                                               const float* __restrict__ lp,
                                               unsigned short* __restrict__ aob, int S){
  int q = blockIdx.x, t = threadIdx.x;
  int h = t >> 5;
  float o = 0.f, l = 0.f;
  #pragma unroll
  for(int s=0;s<KS;s++) o += Op[(size_t)s*S*256 + q*256 + t];
  #pragma unroll
  for(int s=0;s<KS;s++) l += lp[s*S*8 + q*8 + h];
  aob[q*256 + t] = f2bf(o / l);
}

extern "C" void kernel_launch(void* const* d_in, const int* in_sizes, int n_in,
                              void* d_out, int out_size, void* d_ws, size_t ws_size,
                              hipStream_t stream) {
  const float* x   = (const float*)d_in[0];
  const int*   ei  = (const int*)d_in[1];
  const float* W0  = (const float*)d_in[2];
  const float* as0 = (const float*)d_in[3];
  const float* ad0 = (const float*)d_in[4];
  const float* b0  = (const float*)d_in[5];
  const float* W1  = (const float*)d_in[6];
  const float* as1 = (const float*)d_in[7];
  const float* ad1 = (const float*)d_in[8];
  const float* b1  = (const float*)d_in[9];
  const float* W2  = (const float*)d_in[10];
  const float* as2 = (const float*)d_in[11];
  const float* ad2 = (const float*)d_in[12];
  const float* b2  = (const float*)d_in[13];
  const float* g0  = (const float*)d_in[14];
  const float* be0 = (const float*)d_in[15];
  const float* g1  = (const float*)d_in[16];
  const float* be1 = (const float*)d_in[17];
  const float* g2  = (const float*)d_in[18];
  const float* be2 = (const float*)d_in[19];
  const float* wq  = (const float*)d_in[20];
  const float* bq  = (const float*)d_in[21];
  const float* wk  = (const float*)d_in[22];
  const float* bk  = (const float*)d_in[23];
  const float* wv  = (const float*)d_in[24];
  const float* bv  = (const float*)d_in[25];
  const float* wo  = (const float*)d_in[26];
  const float* bo  = (const float*)d_in[27];
  float* out = (float*)d_out;

  const int N = 4096;
  const int E = in_sizes[1] / 2;
  const int Etot = E + N;

  char* p = (char*)d_ws;
  auto alloc = [&](size_t bytes){ char* r = p; p += (bytes + 255) & ~(size_t)255; return r; };

  float* xl   = (float*)alloc(N*512*4);
  float* h0   = (float*)alloc(N*512*4);
  float* als  = (float*)alloc(N*4*4);
  float* ald  = (float*)alloc(N*4*4);
  unsigned short* xb  = (unsigned short*)alloc(N*128*2);
  unsigned short* xlb = (unsigned short*)alloc(N*512*2);
  unsigned short* h0b = (unsigned short*)alloc(N*512*2);
  unsigned short* h1b = (unsigned short*)alloc(N*512*2);
  unsigned short* h2b = (unsigned short*)alloc(N*256*2);
  unsigned short* Qh  = (unsigned short*)alloc(N*256*2);
  unsigned short* Kh  = (unsigned short*)alloc(N*256*2);
  unsigned short* Vh  = (unsigned short*)alloc(N*256*2);
  unsigned short* Vt  = (unsigned short*)alloc(256*N*2);
  unsigned short* aob = (unsigned short*)alloc(N*256*2);
  unsigned short* W0t = (unsigned short*)alloc(512*128*2);
  unsigned short* W1t = (unsigned short*)alloc(512*512*2);
  unsigned short* W2t = (unsigned short*)alloc(256*512*2);
  unsigned short* wqt = (unsigned short*)alloc(256*256*2);
  unsigned short* wkt = (unsigned short*)alloc(256*256*2);
  unsigned short* wvt = (unsigned short*)alloc(256*256*2);
  unsigned short* wot = (unsigned short*)alloc(256*256*2);
  float* Op = (float*)alloc((size_t)KS*N*256*4);
  float* lp = (float*)alloc((size_t)KS*N*8*4);
  int* hist = (int*)alloc(N*4);
  int* wcnt = (int*)alloc(N*4);
  int* rp   = (int*)alloc((N+2)*4);
  int* col  = (int*)alloc(Etot*4);

  // ---------- fused prep (x conv + all weight transposes) ----------
  prep<<<4864, 256, 0, stream>>>(x, xb, W0, W0t, W1, W1t, W2, W2t,
                                 wq, wqt, wk, wkt, wv, wvt, wo, wot);

  // ---------- CSR build (by destination) ----------
  zero_ints<<<(N+255)/256, 256, 0, stream>>>(hist, N);
  csr_count<<<(Etot+255)/256, 256, 0, stream>>>(ei, E, Etot, hist);
  csr_scan<<<1, 1024, 0, stream>>>(hist, rp, wcnt, N);
  csr_scatter<<<(Etot+255)/256, 256, 0, stream>>>(ei, E, Etot, wcnt, col);

  // ---------- GAT layer 0: 128 -> 4x128 (512) ----------
  gemm_mfma<<<dim3(512/64, N/64), 256, 0, stream>>>(xb, W0t, nullptr, xl, xlb, N, 128, 512);
  attn_coef<<<N, 256, 0, stream>>>(xl, as0, ad0, als, ald, 4, 128);
  gat_gather_ln<<<N, 256, 0, stream>>>(rp, col, xlb, als, ald, b0, g0, be0,
                                       nullptr, h0, h0b, 512, 7, 4, 1);

  // ---------- GAT layer 1: 512 -> 4x128 (512), residual ----------
  gemm_mfma<<<dim3(512/64, N/64), 256, 0, stream>>>(h0b, W1t, nullptr, xl, xlb, N, 512, 512);
  attn_coef<<<N, 256, 0, stream>>>(xl, as1, ad1, als, ald, 4, 128);
  gat_gather_ln<<<N, 256, 0, stream>>>(rp, col, xlb, als, ald, b1, g1, be1,
                                       h0, nullptr, h1b, 512, 7, 4, 1);

  // ---------- GAT layer 2: 512 -> 1x256, 1 head, no ELU ----------
  gemm_mfma<<<dim3(256/64, N/64), 256, 0, stream>>>(h1b, W2t, nullptr, xl, xlb, N, 512, 256);
  attn_coef<<<N, 256, 0, stream>>>(xl, as2, ad2, als, ald, 1, 256);
  gat_gather_ln<<<N, 256, 0, stream>>>(rp, col, xlb, als, ald, b2, g2, be2,
                                       nullptr, nullptr, h2b, 256, 8, 1, 0);

  // ---------- dense MHA over 4096 nodes (bf16 MFMA, flash-decode) ----------
  gemm_mfma<<<dim3(256/64, N/64), 256, 0, stream>>>(h2b, wqt, bq, nullptr, Qh, N, 256, 256);
  gemm_mfma<<<dim3(256/64, N/64), 256, 0, stream>>>(h2b, wkt, bk, nullptr, Kh, N, 256, 256);
  gemm_mfma<<<dim3(256/64, N/64), 256, 0, stream>>>(h2b, wvt, bv, nullptr, Vh, N, 256, 256);
  transpose_v<<<dim3(N/64, 4), 256, 0, stream>>>(Vh, Vt, N);
  attention5<<<dim3(N/64, 8, KS), 256, 0, stream>>>(Qh, Kh, Vt, Op, lp, N);
  combine<<<N, 256, 0, stream>>>(Op, lp, aob, N);
  gemm_mfma<<<dim3(256/64, N/64), 256, 0, stream>>>(aob, wot, bo, out, nullptr, N, 256, 256);
}

// Round 6
// 394.977 us; speedup vs baseline: 9.9883x; 1.1515x over previous
//
#include <hip/hip_runtime.h>
#include <math.h>

typedef __attribute__((ext_vector_type(8))) short short8;
typedef __attribute__((ext_vector_type(4))) float float4v;

#define QS 0.2550354f   // (1/sqrt(32)) * log2(e), folded into wq/bq

__device__ __forceinline__ float waveReduceSum(float v){
  #pragma unroll
  for(int o=32;o>0;o>>=1) v += __shfl_down(v,o,64);
  return v;
}

__device__ __forceinline__ unsigned short f2bf(float f){
  unsigned int u = __float_as_uint(f);
  return (unsigned short)((u + 0x7FFFu + ((u>>16)&1u)) >> 16);
}
__device__ __forceinline__ float bf2f(unsigned short u){
  return __uint_as_float(((unsigned int)u)<<16);
}

// ---------------- fused prep: x->bf16 + weight transposes + qkv concat ----------------
// blocks: [0,2048) x conv; [2048,2304) W0t; [2304,3328) W1t; [3328,3840) W2t;
// [3840,4096) wq->wqkvt rows 0..255 (scaled QS); [4096,4352) wk->rows 256..511;
// [4352,4608) wv->rows 512..767; [4608,4864) wo->wot; 4864: bqkv.
__global__ __launch_bounds__(256) void prep(const float* __restrict__ x, unsigned short* __restrict__ xb,
                     const float* __restrict__ W0, unsigned short* __restrict__ W0t,
                     const float* __restrict__ W1, unsigned short* __restrict__ W1t,
                     const float* __restrict__ W2, unsigned short* __restrict__ W2t,
                     const float* __restrict__ wq, const float* __restrict__ wk,
                     const float* __restrict__ wv, unsigned short* __restrict__ wqkvt,
                     const float* __restrict__ bq, const float* __restrict__ bk,
                     const float* __restrict__ bv, float* __restrict__ bqkv,
                     const float* __restrict__ wo, unsigned short* __restrict__ wot){
  int b = blockIdx.x, t = threadIdx.x;
  if(b < 2048){ int i = b*256 + t; xb[i] = f2bf(x[i]); return; }
  if(b == 4864){ bqkv[t] = bq[t]*QS; bqkv[256+t] = bk[t]; bqkv[512+t] = bv[t]; return; }
  const float* src; unsigned short* dst; int K,N,base,roff; float sc = 1.f;
  if(b<2304){src=W0;dst=W0t;K=128;N=512;base=2048;roff=0;}
  else if(b<3328){src=W1;dst=W1t;K=512;N=512;base=2304;roff=0;}
  else if(b<3840){src=W2;dst=W2t;K=512;N=256;base=3328;roff=0;}
  else if(b<4096){src=wq;dst=wqkvt;K=256;N=256;base=3840;roff=0;sc=QS;}
  else if(b<4352){src=wk;dst=wqkvt;K=256;N=256;base=4096;roff=256;}
  else if(b<4608){src=wv;dst=wqkvt;K=256;N=256;base=4352;roff=512;}
  else            {src=wo;dst=wot;K=256;N=256;base=4608;roff=0;}
  int idx = (b-base)*256 + t;
  int k = idx / N, n = idx - k*N;
  dst[(n+roff)*K + k] = f2bf(src[idx]*sc);
}

// --------- Wsd[16][K] bf16: rows 0..H-1 = W@a_s per head, 4..4+H-1 = W@a_d, rest 0 ---------
__global__ __launch_bounds__(256) void make_wsd(const float* __restrict__ W0, const float* __restrict__ as0, const float* __restrict__ ad0, unsigned short* __restrict__ S0,
                                                const float* __restrict__ W1, const float* __restrict__ as1, const float* __restrict__ ad1, unsigned short* __restrict__ S1,
                                                const float* __restrict__ W2, const float* __restrict__ as2, const float* __restrict__ ad2, unsigned short* __restrict__ S2){
  int b = blockIdx.x, t = threadIdx.x;
  const float *W,*as,*ad; unsigned short* S; int K,C,H,k;
  if(b<128){W=W0;as=as0;ad=ad0;S=S0;K=128;C=128;H=4;k=b;}
  else if(b<640){W=W1;as=as1;ad=ad1;S=S1;K=512;C=128;H=4;k=b-128;}
  else {W=W2;as=as2;ad=ad2;S=S2;K=512;C=256;H=1;k=b-640;}
  int D = H*C;
  __shared__ float s1[4], s2[4];
  int lane=t&63, wid=t>>6;
  for(int h=0;h<H;h++){
    float ps=0.f, pd=0.f;
    for(int c=t;c<C;c+=256){
      float wv = W[k*D + h*C + c];
      ps += wv*as[h*C+c];
      pd += wv*ad[h*C+c];
    }
    ps = waveReduceSum(ps); pd = waveReduceSum(pd);
    if(lane==0){ s1[wid]=ps; s2[wid]=pd; }
    __syncthreads();
    if(t==0){
      float u=s1[0]+s1[1]+s1[2]+s1[3], v=s2[0]+s2[1]+s2[2]+s2[3];
      S[h*K+k]=f2bf(u); S[(4+h)*K+k]=f2bf(v);
    }
    __syncthreads();
  }
  if(t==0){
    for(int h=H;h<4;h++){ S[h*K+k]=0; S[(4+h)*K+k]=0; }
    for(int r=8;r<16;r++) S[r*K+k]=0;
  }
}

// ---------------- MFMA bf16 GEMM, zero-LDS; optional fused als/ald ----------------
// A bf16 [M,K]; Bt bf16 [N,K]. Outputs: C fp32 and/or Cb bf16.
// If Wsd: blockIdx.x==0 blocks also compute als/ald = A @ Wsd^T (stride 4).
__global__ __launch_bounds__(256) void gemm_mfma(const unsigned short* __restrict__ A,
                                                 const unsigned short* __restrict__ Bt,
                                                 const float* __restrict__ bias,
                                                 float* __restrict__ C,
                                                 unsigned short* __restrict__ Cb,
                                                 const unsigned short* __restrict__ Wsd,
                                                 float* __restrict__ als,
                                                 float* __restrict__ ald,
                                                 int M, int K, int N){
  int t = threadIdx.x, lane = t & 63, w = t >> 6;
  int m = lane & 15, g = lane >> 4;
  int bm = blockIdx.y * 64, bn = blockIdx.x * 64;

  const unsigned short* Ap = A + (bm + w*16 + m)*K + g*8;
  const unsigned short* Bp = Bt + (bn + m)*K + g*8;
  bool doC = (Wsd != nullptr) && (blockIdx.x == 0);

  float4v acc[4];
  #pragma unroll
  for(int nt=0;nt<4;nt++) acc[nt] = (float4v){0.f,0.f,0.f,0.f};
  float4v acc2 = (float4v){0.f,0.f,0.f,0.f};

  for(int k0=0;k0<K;k0+=32){
    short8 aA = *(const short8*)(Ap + k0);
    #pragma unroll
    for(int nt=0;nt<4;nt++){
      short8 bB = *(const short8*)(Bp + nt*16*K + k0);
      acc[nt] = __builtin_amdgcn_mfma_f32_16x16x32_bf16(aA, bB, acc[nt], 0,0,0);
    }
    if(doC){
      short8 bW = *(const short8*)(Wsd + m*K + g*8 + k0);
      acc2 = __builtin_amdgcn_mfma_f32_16x16x32_bf16(aA, bW, acc2, 0,0,0);
    }
  }
  #pragma unroll
  for(int nt=0;nt<4;nt++){
    int col = bn + nt*16 + m;
    float bv = bias ? bias[col] : 0.f;
    #pragma unroll
    for(int r=0;r<4;r++){
      int row = bm + w*16 + g*4 + r;
      float v = acc[nt][r] + bv;
      if(C)  C[row*N + col]  = v;
      if(Cb) Cb[row*N + col] = f2bf(v);
    }
  }
  if(doC){
    #pragma unroll
    for(int r=0;r<4;r++){
      int row = bm + w*16 + g*4 + r;
      if(m<4)      als[row*4 + m]     = acc2[r];
      else if(m<8) ald[row*4 + (m-4)] = acc2[r];
    }
  }
}

// ---------------- CSR build ----------------
__global__ void zero_ints(int* p, int n){
  int i = blockIdx.x*256 + threadIdx.x;
  if(i<n) p[i]=0;
}

__global__ void csr_count(const int* __restrict__ ei, int E, int Etot,
                          int* __restrict__ hist){
  int e = blockIdx.x*256 + threadIdx.x;
  if(e>=Etot) return;
  int d = (e<E) ? (ei[E+e]&4095) : (e-E);
  atomicAdd(&hist[d], 1);
}

__global__ __launch_bounds__(1024) void csr_scan(const int* __restrict__ hist,
                                                 int* __restrict__ row_ptr,
                                                 int* __restrict__ wcnt, int N){
  __shared__ int sh[1024];
  int t = threadIdx.x;
  int base[4];
  int s = 0;
  #pragma unroll
  for(int i=0;i<4;i++){ base[i]=s; s += hist[t*4+i]; }
  sh[t] = s;
  __syncthreads();
  for(int off=1; off<1024; off<<=1){
    int x = (t>=off) ? sh[t-off] : 0;
    __syncthreads();
    sh[t] += x;
    __syncthreads();
  }
  int excl = (t==0) ? 0 : sh[t-1];
  #pragma unroll
  for(int i=0;i<4;i++){
    row_ptr[t*4+i] = excl + base[i];
    wcnt[t*4+i]    = excl + base[i];
  }
  if(t==1023) row_ptr[N] = excl + s;
}

__global__ void csr_scatter(const int* __restrict__ ei, int E, int Etot,
                            int* __restrict__ wcnt, int* __restrict__ col){
  int e = blockIdx.x*256 + threadIdx.x;
  if(e>=Etot) return;
  int s,d;
  if(e<E){ s=ei[e]&4095; d=ei[E+e]&4095; } else { s=d=e-E; }
  int pos = atomicAdd(&wcnt[d], 1);
  col[pos] = s;
}

// ------- fused GAT gather + softmax + bias + ELU + LayerNorm (+residual) -------
// blockDim = D/2; each thread owns 2 channels via one packed dword load per edge.
__global__ void gat_gather_ln(const int* __restrict__ rp,
                              const int* __restrict__ col,
                              const unsigned short* __restrict__ xlb,
                              const float* __restrict__ als,
                              const float* __restrict__ ald,
                              const float* __restrict__ bias,
                              const float* __restrict__ gw,
                              const float* __restrict__ be,
                              const float* __restrict__ res,
                              float* __restrict__ out,
                              unsigned short* __restrict__ outb,
                              int D, int logC, int do_elu){
  int n = blockIdx.x, t = threadIdx.x;
  int c0 = t*2;
  int h = c0 >> logC;
  float adv = ald[n*4+h];
  int start = rp[n], end = rp[n+1];
  const unsigned int* xw = (const unsigned int*)xlb;
  int rowW = D >> 1;
  float acc0=0.f, acc1=0.f, den=0.f;
  for(int j=start;j<end;j++){
    int s = col[j];
    float a = als[s*4+h] + adv;
    a = a>0.f ? a : 0.2f*a;
    float p = __expf(a);
    unsigned int u = xw[s*rowW + t];
    acc0 += p * bf2f((unsigned short)(u & 0xffffu));
    acc1 += p * bf2f((unsigned short)(u >> 16));
    den += p;
  }
  float inv_d = 1.f/(den + 1e-16f);
  float v0 = acc0*inv_d + bias[c0];
  float v1 = acc1*inv_d + bias[c0+1];
  if(do_elu){
    v0 = v0>0.f ? v0 : expm1f(v0);
    v1 = v1>0.f ? v1 : expm1f(v1);
  }
  __shared__ float sh[4];
  int lane=t&63, wid=t>>6, nw = blockDim.x>>6;
  float sum = waveReduceSum(v0+v1);
  if(lane==0) sh[wid]=sum;
  __syncthreads();
  float mean = 0.f;
  for(int i=0;i<nw;i++) mean += sh[i];
  mean /= (float)D;
  __syncthreads();
  float d0 = v0-mean, d1 = v1-mean;
  float vs = waveReduceSum(d0*d0 + d1*d1);
  if(lane==0) sh[wid]=vs;
  __syncthreads();
  float var = 0.f;
  for(int i=0;i<nw;i++) var += sh[i];
  var /= (float)D;
  float inv = rsqrtf(var + 1e-5f);
  float y0 = d0*inv*gw[c0]   + be[c0];
  float y1 = d1*inv*gw[c0+1] + be[c0+1];
  if(res){ float2 rv = *(const float2*)(res + n*D + c0); y0 += rv.x; y1 += rv.y; }
  if(out) *(float2*)(out + n*D + c0) = make_float2(y0, y1);
  if(outb) ((unsigned int*)outb)[n*rowW + t] =
      (unsigned int)f2bf(y0) | ((unsigned int)f2bf(y1) << 16);
}

// --------- V transpose: QKV[:,512:768] bf16 [S,768] -> Vt bf16 [256,S] ---------
__global__ __launch_bounds__(256) void transpose_v(const unsigned short* __restrict__ QKV,
                                                   unsigned short* __restrict__ Vt, int S){
  __shared__ unsigned short tile[64][72];
  int bs = blockIdx.x*64;   // key block
  int bd = blockIdx.y*64;   // dim block
  int t = threadIdx.x;
  int r8 = t>>3, c8 = (t&7)*8;
  #pragma unroll
  for(int it=0; it<2; it++){
    int row = r8 + it*32;
    short8 v = *(const short8*)(QKV + (bs+row)*768 + 512 + bd + c8);
    *(short8*)&tile[row][c8] = v;
  }
  __syncthreads();
  #pragma unroll
  for(int it=0; it<2; it++){
    int drow = r8 + it*32;
    short8 o;
    #pragma unroll
    for(int j=0;j<8;j++) o[j] = (short)tile[c8+j][drow];
    *(short8*)(Vt + (bd+drow)*S + bs + c8) = o;
  }
}

// --------- MFMA bf16 MHA, flash-decode: block=(64q, head, ksplit) ---------
// Q pre-scaled by (1/sqrt(dk))*log2e -> p = exp2(QK). Partial O,l to scratch.
#define KS 4
__global__ __launch_bounds__(256) void attention5(const unsigned short* __restrict__ QKV,
                                                  const unsigned short* __restrict__ Vt,
                                                  float* __restrict__ Op,
                                                  float* __restrict__ lp, int S){
  const int RS = 768;
  int qb = blockIdx.x * 64;
  int h  = blockIdx.y;
  int ks = blockIdx.z;
  int t  = threadIdx.x;
  int lane = t & 63, w = t >> 6;
  int m = lane & 15, g = lane >> 4;

  __shared__ unsigned short Ps[64*72];   // [q][key], stride 72
  __shared__ unsigned short Vs[32*72];   // [dim][key], stride 72

  short8 aQ = *(const short8*)(QKV + (qb + w*16 + m)*RS + h*32 + g*8);

  float4v o0 = {0.f,0.f,0.f,0.f}, o1 = {0.f,0.f,0.f,0.f};
  float l[4] = {0.f,0.f,0.f,0.f};

  int r8 = t>>3, c8 = (t&7)*8;
  int kA = ks*(S/KS), kB = kA + S/KS;

  for(int kt=kA; kt<kB; kt+=64){
    short8 v = *(const short8*)(Vt + (h*32 + r8)*S + kt + c8);
    *(short8*)&Vs[r8*72 + c8] = v;
    __syncthreads();

    #pragma unroll
    for(int nt=0;nt<4;nt++){
      short8 bK = *(const short8*)(QKV + (kt + nt*16 + m)*RS + 256 + h*32 + g*8);
      float4v acc = {0.f,0.f,0.f,0.f};
      acc = __builtin_amdgcn_mfma_f32_16x16x32_bf16(aQ, bK, acc, 0,0,0);
      #pragma unroll
      for(int r=0;r<4;r++){
        float p = exp2f(acc[r]);
        l[r] += p;
        Ps[(w*16 + g*4 + r)*72 + nt*16 + m] = f2bf(p);
      }
    }

    #pragma unroll
    for(int kh=0;kh<2;kh++){
      short8 aP  = *(const short8*)&Ps[(w*16 + m)*72 + kh*32 + g*8];
      short8 bV0 = *(const short8*)&Vs[(m)*72    + kh*32 + g*8];
      short8 bV1 = *(const short8*)&Vs[(16+m)*72 + kh*32 + g*8];
      o0 = __builtin_amdgcn_mfma_f32_16x16x32_bf16(aP, bV0, o0, 0,0,0);
      o1 = __builtin_amdgcn_mfma_f32_16x16x32_bf16(aP, bV1, o1, 0,0,0);
    }
    __syncthreads();
  }

  #pragma unroll
  for(int r=0;r<4;r++){
    float li = l[r];
    li += __shfl_xor(li,1,64); li += __shfl_xor(li,2,64);
    li += __shfl_xor(li,4,64); li += __shfl_xor(li,8,64);
    l[r] = li;
  }
  float* Ob = Op + (size_t)ks*S*256;
  #pragma unroll
  for(int r=0;r<4;r++){
    int q = qb + w*16 + g*4 + r;
    Ob[q*256 + h*32 + m]      = o0[r];
    Ob[q*256 + h*32 + 16 + m] = o1[r];
    if(m==0) lp[ks*S*8 + q*8 + h] = l[r];
  }
}

__global__ __launch_bounds__(256) void combine(const float* __restrict__ Op,
                                               const float* __restrict__ lp,
                                               unsigned short* __restrict__ aob, int S){
  int q = blockIdx.x, t = threadIdx.x;
  int h = t >> 5;
  float o = 0.f, l = 0.f;
  #pragma unroll
  for(int s=0;s<KS;s++) o += Op[(size_t)s*S*256 + q*256 + t];
  #pragma unroll
  for(int s=0;s<KS;s++) l += lp[s*S*8 + q*8 + h];
  aob[q*256 + t] = f2bf(o / l);
}

extern "C" void kernel_launch(void* const* d_in, const int* in_sizes, int n_in,
                              void* d_out, int out_size, void* d_ws, size_t ws_size,
                              hipStream_t stream) {
  const float* x   = (const float*)d_in[0];
  const int*   ei  = (const int*)d_in[1];
  const float* W0  = (const float*)d_in[2];
  const float* as0 = (const float*)d_in[3];
  const float* ad0 = (const float*)d_in[4];
  const float* b0  = (const float*)d_in[5];
  const float* W1  = (const float*)d_in[6];
  const float* as1 = (const float*)d_in[7];
  const float* ad1 = (const float*)d_in[8];
  const float* b1  = (const float*)d_in[9];
  const float* W2  = (const float*)d_in[10];
  const float* as2 = (const float*)d_in[11];
  const float* ad2 = (const float*)d_in[12];
  const float* b2  = (const float*)d_in[13];
  const float* g0  = (const float*)d_in[14];
  const float* be0 = (const float*)d_in[15];
  const float* g1  = (const float*)d_in[16];
  const float* be1 = (const float*)d_in[17];
  const float* g2  = (const float*)d_in[18];
  const float* be2 = (const float*)d_in[19];
  const float* wq  = (const float*)d_in[20];
  const float* bq  = (const float*)d_in[21];
  const float* wk  = (const float*)d_in[22];
  const float* bk  = (const float*)d_in[23];
  const float* wv  = (const float*)d_in[24];
  const float* bv  = (const float*)d_in[25];
  const float* wo  = (const float*)d_in[26];
  const float* bo  = (const float*)d_in[27];
  float* out = (float*)d_out;

  const int N = 4096;
  const int E = in_sizes[1] / 2;
  const int Etot = E + N;

  char* p = (char*)d_ws;
  auto alloc = [&](size_t bytes){ char* r = p; p += (bytes + 255) & ~(size_t)255; return r; };

  float* h0   = (float*)alloc(N*512*4);
  float* als  = (float*)alloc(N*4*4);
  float* ald  = (float*)alloc(N*4*4);
  unsigned short* xb   = (unsigned short*)alloc(N*128*2);
  unsigned short* xlb  = (unsigned short*)alloc(N*512*2);
  unsigned short* h0b  = (unsigned short*)alloc(N*512*2);
  unsigned short* h1b  = (unsigned short*)alloc(N*512*2);
  unsigned short* h2b  = (unsigned short*)alloc(N*256*2);
  unsigned short* QKVb = (unsigned short*)alloc((size_t)N*768*2);
  unsigned short* Vt   = (unsigned short*)alloc(256*N*2);
  unsigned short* aob  = (unsigned short*)alloc(N*256*2);
  unsigned short* W0t  = (unsigned short*)alloc(512*128*2);
  unsigned short* W1t  = (unsigned short*)alloc(512*512*2);
  unsigned short* W2t  = (unsigned short*)alloc(256*512*2);
  unsigned short* wqkvt= (unsigned short*)alloc(768*256*2);
  float* bqkv = (float*)alloc(768*4);
  unsigned short* wot  = (unsigned short*)alloc(256*256*2);
  unsigned short* Wsd0 = (unsigned short*)alloc(16*128*2);
  unsigned short* Wsd1 = (unsigned short*)alloc(16*512*2);
  unsigned short* Wsd2 = (unsigned short*)alloc(16*512*2);
  float* Op = (float*)alloc((size_t)KS*N*256*4);
  float* lp = (float*)alloc((size_t)KS*N*8*4);
  int* hist = (int*)alloc(N*4);
  int* wcnt = (int*)alloc(N*4);
  int* rp   = (int*)alloc((N+2)*4);
  int* col  = (int*)alloc(Etot*4);

  // ---------- prep ----------
  prep<<<4865, 256, 0, stream>>>(x, xb, W0, W0t, W1, W1t, W2, W2t,
                                 wq, wk, wv, wqkvt, bq, bk, bv, bqkv, wo, wot);
  make_wsd<<<1152, 256, 0, stream>>>(W0, as0, ad0, Wsd0, W1, as1, ad1, Wsd1, W2, as2, ad2, Wsd2);

  // ---------- CSR build (by destination) ----------
  zero_ints<<<(N+255)/256, 256, 0, stream>>>(hist, N);
  csr_count<<<(Etot+255)/256, 256, 0, stream>>>(ei, E, Etot, hist);
  csr_scan<<<1, 1024, 0, stream>>>(hist, rp, wcnt, N);
  csr_scatter<<<(Etot+255)/256, 256, 0, stream>>>(ei, E, Etot, wcnt, col);

  // ---------- GAT layer 0: 128 -> 4x128 (512) ----------
  gemm_mfma<<<dim3(8, 64), 256, 0, stream>>>(xb, W0t, nullptr, nullptr, xlb, Wsd0, als, ald, N, 128, 512);
  gat_gather_ln<<<N, 256, 0, stream>>>(rp, col, xlb, als, ald, b0, g0, be0,
                                       nullptr, h0, h0b, 512, 7, 1);

  // ---------- GAT layer 1: 512 -> 4x128 (512), residual ----------
  gemm_mfma<<<dim3(8, 64), 256, 0, stream>>>(h0b, W1t, nullptr, nullptr, xlb, Wsd1, als, ald, N, 512, 512);
  gat_gather_ln<<<N, 256, 0, stream>>>(rp, col, xlb, als, ald, b1, g1, be1,
                                       h0, nullptr, h1b, 512, 7, 1);

  // ---------- GAT layer 2: 512 -> 1x256, 1 head, no ELU ----------
  gemm_mfma<<<dim3(4, 64), 256, 0, stream>>>(h1b, W2t, nullptr, nullptr, xlb, Wsd2, als, ald, N, 512, 256);
  gat_gather_ln<<<N, 128, 0, stream>>>(rp, col, xlb, als, ald, b2, g2, be2,
                                       nullptr, nullptr, h2b, 256, 8, 0);

  // ---------- dense MHA (bf16 MFMA, flash-decode, fused QKV) ----------
  gemm_mfma<<<dim3(12, 64), 256, 0, stream>>>(h2b, wqkvt, bqkv, nullptr, QKVb, nullptr, nullptr, nullptr, N, 256, 768);
  transpose_v<<<dim3(N/64, 4), 256, 0, stream>>>(QKVb, Vt, N);
  attention5<<<dim3(N/64, 8, KS), 256, 0, stream>>>(QKVb, Vt, Op, lp, N);
  combine<<<N, 256, 0, stream>>>(Op, lp, aob, N);
  gemm_mfma<<<dim3(4, 64), 256, 0, stream>>>(aob, wot, bo, out, nullptr, nullptr, nullptr, nullptr, N, 256, 256);
}

// Round 7
// 383.909 us; speedup vs baseline: 10.2762x; 1.0288x over previous
//
#include <hip/hip_runtime.h>
#include <math.h>

typedef __attribute__((ext_vector_type(8))) short short8;
typedef __attribute__((ext_vector_type(4))) float float4v;

#define QS 0.2550354f   // (1/sqrt(32)) * log2(e), folded into wq/bq

__device__ __forceinline__ float waveReduceSum(float v){
  #pragma unroll
  for(int o=32;o>0;o>>=1) v += __shfl_down(v,o,64);
  return v;
}

__device__ __forceinline__ unsigned short f2bf(float f){
  unsigned int u = __float_as_uint(f);
  return (unsigned short)((u + 0x7FFFu + ((u>>16)&1u)) >> 16);
}
__device__ __forceinline__ float bf2f(unsigned short u){
  return __uint_as_float(((unsigned int)u)<<16);
}

// ---------------- fused prep: x->bf16 + weight transposes + qkv concat ----------------
__global__ __launch_bounds__(256) void prep(const float* __restrict__ x, unsigned short* __restrict__ xb,
                     const float* __restrict__ W0, unsigned short* __restrict__ W0t,
                     const float* __restrict__ W1, unsigned short* __restrict__ W1t,
                     const float* __restrict__ W2, unsigned short* __restrict__ W2t,
                     const float* __restrict__ wq, const float* __restrict__ wk,
                     const float* __restrict__ wv, unsigned short* __restrict__ wqkvt,
                     const float* __restrict__ bq, const float* __restrict__ bk,
                     const float* __restrict__ bv, float* __restrict__ bqkv,
                     const float* __restrict__ wo, unsigned short* __restrict__ wot){
  int b = blockIdx.x, t = threadIdx.x;
  if(b < 2048){ int i = b*256 + t; xb[i] = f2bf(x[i]); return; }
  if(b == 4864){ bqkv[t] = bq[t]*QS; bqkv[256+t] = bk[t]; bqkv[512+t] = bv[t]; return; }
  const float* src; unsigned short* dst; int K,N,base,roff; float sc = 1.f;
  if(b<2304){src=W0;dst=W0t;K=128;N=512;base=2048;roff=0;}
  else if(b<3328){src=W1;dst=W1t;K=512;N=512;base=2304;roff=0;}
  else if(b<3840){src=W2;dst=W2t;K=512;N=256;base=3328;roff=0;}
  else if(b<4096){src=wq;dst=wqkvt;K=256;N=256;base=3840;roff=0;sc=QS;}
  else if(b<4352){src=wk;dst=wqkvt;K=256;N=256;base=4096;roff=256;}
  else if(b<4608){src=wv;dst=wqkvt;K=256;N=256;base=4352;roff=512;}
  else            {src=wo;dst=wot;K=256;N=256;base=4608;roff=0;}
  int idx = (b-base)*256 + t;
  int k = idx / N, n = idx - k*N;
  dst[(n+roff)*K + k] = f2bf(src[idx]*sc);
}

// --------- Wsd[16][K] bf16: rows 0..H-1 = W@a_s per head, 4..4+H-1 = W@a_d, rest 0 ---------
__global__ __launch_bounds__(256) void make_wsd(const float* __restrict__ W0, const float* __restrict__ as0, const float* __restrict__ ad0, unsigned short* __restrict__ S0,
                                                const float* __restrict__ W1, const float* __restrict__ as1, const float* __restrict__ ad1, unsigned short* __restrict__ S1,
                                                const float* __restrict__ W2, const float* __restrict__ as2, const float* __restrict__ ad2, unsigned short* __restrict__ S2){
  int b = blockIdx.x, t = threadIdx.x;
  const float *W,*as,*ad; unsigned short* S; int K,C,H,k;
  if(b<128){W=W0;as=as0;ad=ad0;S=S0;K=128;C=128;H=4;k=b;}
  else if(b<640){W=W1;as=as1;ad=ad1;S=S1;K=512;C=128;H=4;k=b-128;}
  else {W=W2;as=as2;ad=ad2;S=S2;K=512;C=256;H=1;k=b-640;}
  int D = H*C;
  __shared__ float s1[4], s2[4];
  int lane=t&63, wid=t>>6;
  for(int h=0;h<H;h++){
    float ps=0.f, pd=0.f;
    for(int c=t;c<C;c+=256){
      float wv = W[k*D + h*C + c];
      ps += wv*as[h*C+c];
      pd += wv*ad[h*C+c];
    }
    ps = waveReduceSum(ps); pd = waveReduceSum(pd);
    if(lane==0){ s1[wid]=ps; s2[wid]=pd; }
    __syncthreads();
    if(t==0){
      float u=s1[0]+s1[1]+s1[2]+s1[3], v=s2[0]+s2[1]+s2[2]+s2[3];
      S[h*K+k]=f2bf(u); S[(4+h)*K+k]=f2bf(v);
    }
    __syncthreads();
  }
  if(t==0){
    for(int h=H;h<4;h++){ S[h*K+k]=0; S[(4+h)*K+k]=0; }
    for(int r=8;r<16;r++) S[r*K+k]=0;
  }
}

// ---------------- MFMA bf16 GEMM, zero-LDS; optional fused als/ald ----------------
__global__ __launch_bounds__(256) void gemm_mfma(const unsigned short* __restrict__ A,
                                                 const unsigned short* __restrict__ Bt,
                                                 const float* __restrict__ bias,
                                                 float* __restrict__ C,
                                                 unsigned short* __restrict__ Cb,
                                                 const unsigned short* __restrict__ Wsd,
                                                 float* __restrict__ als,
                                                 float* __restrict__ ald,
                                                 int M, int K, int N){
  int t = threadIdx.x, lane = t & 63, w = t >> 6;
  int m = lane & 15, g = lane >> 4;
  int bm = blockIdx.y * 64, bn = blockIdx.x * 64;

  const unsigned short* Ap = A + (bm + w*16 + m)*K + g*8;
  const unsigned short* Bp = Bt + (bn + m)*K + g*8;
  bool doC = (Wsd != nullptr) && (blockIdx.x == 0);

  float4v acc[4];
  #pragma unroll
  for(int nt=0;nt<4;nt++) acc[nt] = (float4v){0.f,0.f,0.f,0.f};
  float4v acc2 = (float4v){0.f,0.f,0.f,0.f};

  for(int k0=0;k0<K;k0+=32){
    short8 aA = *(const short8*)(Ap + k0);
    #pragma unroll
    for(int nt=0;nt<4;nt++){
      short8 bB = *(const short8*)(Bp + nt*16*K + k0);
      acc[nt] = __builtin_amdgcn_mfma_f32_16x16x32_bf16(aA, bB, acc[nt], 0,0,0);
    }
    if(doC){
      short8 bW = *(const short8*)(Wsd + m*K + g*8 + k0);
      acc2 = __builtin_amdgcn_mfma_f32_16x16x32_bf16(aA, bW, acc2, 0,0,0);
    }
  }
  #pragma unroll
  for(int nt=0;nt<4;nt++){
    int col = bn + nt*16 + m;
    float bv = bias ? bias[col] : 0.f;
    #pragma unroll
    for(int r=0;r<4;r++){
      int row = bm + w*16 + g*4 + r;
      float v = acc[nt][r] + bv;
      if(C)  C[row*N + col]  = v;
      if(Cb) Cb[row*N + col] = f2bf(v);
    }
  }
  if(doC){
    #pragma unroll
    for(int r=0;r<4;r++){
      int row = bm + w*16 + g*4 + r;
      if(m<4)      als[row*4 + m]     = acc2[r];
      else if(m<8) ald[row*4 + (m-4)] = acc2[r];
    }
  }
}

// ---------------- CSR build ----------------
__global__ void zero_ints(int* p, int n){
  int i = blockIdx.x*256 + threadIdx.x;
  if(i<n) p[i]=0;
}

__global__ void csr_count(const int* __restrict__ ei, int E, int Etot,
                          int* __restrict__ hist){
  int e = blockIdx.x*256 + threadIdx.x;
  if(e>=Etot) return;
  int d = (e<E) ? (ei[E+e]&4095) : (e-E);
  atomicAdd(&hist[d], 1);
}

__global__ __launch_bounds__(1024) void csr_scan(const int* __restrict__ hist,
                                                 int* __restrict__ row_ptr,
                                                 int* __restrict__ wcnt, int N){
  __shared__ int sh[1024];
  int t = threadIdx.x;
  int base[4];
  int s = 0;
  #pragma unroll
  for(int i=0;i<4;i++){ base[i]=s; s += hist[t*4+i]; }
  sh[t] = s;
  __syncthreads();
  for(int off=1; off<1024; off<<=1){
    int x = (t>=off) ? sh[t-off] : 0;
    __syncthreads();
    sh[t] += x;
    __syncthreads();
  }
  int excl = (t==0) ? 0 : sh[t-1];
  #pragma unroll
  for(int i=0;i<4;i++){
    row_ptr[t*4+i] = excl + base[i];
    wcnt[t*4+i]    = excl + base[i];
  }
  if(t==1023) row_ptr[N] = excl + s;
}

__global__ void csr_scatter(const int* __restrict__ ei, int E, int Etot,
                            int* __restrict__ wcnt, int* __restrict__ col){
  int e = blockIdx.x*256 + threadIdx.x;
  if(e>=Etot) return;
  int s,d;
  if(e<E){ s=ei[e]&4095; d=ei[E+e]&4095; } else { s=d=e-E; }
  int pos = atomicAdd(&wcnt[d], 1);
  col[pos] = s;
}

// ------- fused GAT gather + softmax + bias + ELU + LayerNorm (+residual) -------
// Chunked: 128 threads precompute per-edge weights p[j][h] + offsets into LDS;
// inner loop = 2 broadcast LDS reads + 1 coalesced dword + 3 FMA per edge.
#define CE 128
__global__ void gat_gather_ln(const int* __restrict__ rp,
                              const int* __restrict__ col,
                              const unsigned short* __restrict__ xlb,
                              const float* __restrict__ als,
                              const float* __restrict__ ald,
                              const float* __restrict__ bias,
                              const float* __restrict__ gw,
                              const float* __restrict__ be,
                              const float* __restrict__ res,
                              float* __restrict__ out,
                              unsigned short* __restrict__ outb,
                              int D, int logC, int do_elu){
  int n = blockIdx.x, t = threadIdx.x;
  int c0 = t*2;
  int h = c0 >> logC;            // wave-uniform
  int rowW = D >> 1;
  float4 advv = *(const float4*)(ald + n*4);
  float adv_h = ((const float*)&advv)[h];
  (void)adv_h;
  int start = rp[n], end = rp[n+1];
  const unsigned int* xw = (const unsigned int*)xlb;

  __shared__ float pw[CE*4];
  __shared__ int offs[CE];

  float acc0=0.f, acc1=0.f, den=0.f;

  for(int base=start; base<end; base+=CE){
    int cnt = min(CE, end-base);
    __syncthreads();
    if(t < cnt){
      int s = col[base+t];
      offs[t] = s*rowW;
      float4 av = *(const float4*)(als + s*4);
      #pragma unroll
      for(int hh=0;hh<4;hh++){
        float a = ((const float*)&av)[hh] + ((const float*)&advv)[hh];
        a = a>0.f ? a : 0.2f*a;
        pw[t*4+hh] = __expf(a);
      }
    }
    __syncthreads();
    #pragma unroll 4
    for(int j=0;j<cnt;j++){
      float p = pw[j*4+h];
      unsigned int u = xw[offs[j] + t];
      acc0 += p * bf2f((unsigned short)(u & 0xffffu));
      acc1 += p * bf2f((unsigned short)(u >> 16));
      den += p;
    }
  }

  float inv_d = 1.f/(den + 1e-16f);
  float v0 = acc0*inv_d + bias[c0];
  float v1 = acc1*inv_d + bias[c0+1];
  if(do_elu){
    v0 = v0>0.f ? v0 : expm1f(v0);
    v1 = v1>0.f ? v1 : expm1f(v1);
  }
  __shared__ float sh[4];
  int lane=t&63, wid=t>>6, nw = blockDim.x>>6;
  float sum = waveReduceSum(v0+v1);
  if(lane==0) sh[wid]=sum;
  __syncthreads();
  float mean = 0.f;
  for(int i=0;i<nw;i++) mean += sh[i];
  mean /= (float)D;
  __syncthreads();
  float d0 = v0-mean, d1 = v1-mean;
  float vs = waveReduceSum(d0*d0 + d1*d1);
  if(lane==0) sh[wid]=vs;
  __syncthreads();
  float var = 0.f;
  for(int i=0;i<nw;i++) var += sh[i];
  var /= (float)D;
  float inv = rsqrtf(var + 1e-5f);
  float y0 = d0*inv*gw[c0]   + be[c0];
  float y1 = d1*inv*gw[c0+1] + be[c0+1];
  if(res){ float2 rv = *(const float2*)(res + n*D + c0); y0 += rv.x; y1 += rv.y; }
  if(out) *(float2*)(out + n*D + c0) = make_float2(y0, y1);
  if(outb) ((unsigned int*)outb)[n*rowW + t] =
      (unsigned int)f2bf(y0) | ((unsigned int)f2bf(y1) << 16);
}

// --------- V transpose: QKV[:,512:768] bf16 [S,768] -> Vt bf16 [256,S] ---------
__global__ __launch_bounds__(256) void transpose_v(const unsigned short* __restrict__ QKV,
                                                   unsigned short* __restrict__ Vt, int S){
  __shared__ unsigned short tile[64][72];
  int bs = blockIdx.x*64;
  int bd = blockIdx.y*64;
  int t = threadIdx.x;
  int r8 = t>>3, c8 = (t&7)*8;
  #pragma unroll
  for(int it=0; it<2; it++){
    int row = r8 + it*32;
    short8 v = *(const short8*)(QKV + (bs+row)*768 + 512 + bd + c8);
    *(short8*)&tile[row][c8] = v;
  }
  __syncthreads();
  #pragma unroll
  for(int it=0; it<2; it++){
    int drow = r8 + it*32;
    short8 o;
    #pragma unroll
    for(int j=0;j<8;j++) o[j] = (short)tile[c8+j][drow];
    *(short8*)(Vt + (bd+drow)*S + bs + c8) = o;
  }
}

// --------- MFMA bf16 MHA, flash-decode: block=(64q, head, ksplit) ---------
// fp32 P in LDS (round-half-up bias folded into stored bits); PV A-frag built
// with v_perm hi-16 extraction. Q pre-scaled by (1/sqrt(dk))*log2e -> exp2.
#define KS 4
__global__ __launch_bounds__(256) void attention5(const unsigned short* __restrict__ QKV,
                                                  const unsigned short* __restrict__ Vt,
                                                  float* __restrict__ Op,
                                                  float* __restrict__ lp, int S){
  const int RS = 768;
  int qb = blockIdx.x * 64;
  int h  = blockIdx.y;
  int ks = blockIdx.z;
  int t  = threadIdx.x;
  int lane = t & 63, w = t >> 6;
  int m = lane & 15, g = lane >> 4;

  __shared__ float Ps[64*68];            // [q][key] fp32, stride 68 (16B-aligned rows, 2-way-free writes)
  __shared__ unsigned short Vs[32*72];   // [dim][key] bf16, stride 72

  short8 aQ = *(const short8*)(QKV + (qb + w*16 + m)*RS + h*32 + g*8);

  float4v o0 = {0.f,0.f,0.f,0.f}, o1 = {0.f,0.f,0.f,0.f};
  float l[4] = {0.f,0.f,0.f,0.f};

  int r8 = t>>3, c8 = (t&7)*8;
  int kA = ks*(S/KS), kB = kA + S/KS;

  for(int kt=kA; kt<kB; kt+=64){
    short8 v = *(const short8*)(Vt + (h*32 + r8)*S + kt + c8);
    *(short8*)&Vs[r8*72 + c8] = v;
    __syncthreads();

    #pragma unroll
    for(int nt=0;nt<4;nt++){
      short8 bK = *(const short8*)(QKV + (kt + nt*16 + m)*RS + 256 + h*32 + g*8);
      float4v acc = {0.f,0.f,0.f,0.f};
      acc = __builtin_amdgcn_mfma_f32_16x16x32_bf16(aQ, bK, acc, 0,0,0);
      #pragma unroll
      for(int r=0;r<4;r++){
        float pe = exp2f(acc[r]);
        l[r] += pe;
        Ps[(w*16 + g*4 + r)*68 + nt*16 + m] = __uint_as_float(__float_as_uint(pe) + 0x8000u);
      }
    }

    // PV: A-frag from fp32 Ps via v_perm hi-16 packing (rows wave-private, no barrier needed)
    #pragma unroll
    for(int kh=0;kh<2;kh++){
      const float4v pa = *(const float4v*)&Ps[(w*16 + m)*68 + kh*32 + g*8];
      const float4v pb = *(const float4v*)&Ps[(w*16 + m)*68 + kh*32 + g*8 + 4];
      union { unsigned int u[4]; short8 s; } cv;
      cv.u[0] = __builtin_amdgcn_perm(__float_as_uint(pa[1]), __float_as_uint(pa[0]), 0x07060302u);
      cv.u[1] = __builtin_amdgcn_perm(__float_as_uint(pa[3]), __float_as_uint(pa[2]), 0x07060302u);
      cv.u[2] = __builtin_amdgcn_perm(__float_as_uint(pb[1]), __float_as_uint(pb[0]), 0x07060302u);
      cv.u[3] = __builtin_amdgcn_perm(__float_as_uint(pb[3]), __float_as_uint(pb[2]), 0x07060302u);
      short8 aP = cv.s;
      short8 bV0 = *(const short8*)&Vs[(m)*72    + kh*32 + g*8];
      short8 bV1 = *(const short8*)&Vs[(16+m)*72 + kh*32 + g*8];
      o0 = __builtin_amdgcn_mfma_f32_16x16x32_bf16(aP, bV0, o0, 0,0,0);
      o1 = __builtin_amdgcn_mfma_f32_16x16x32_bf16(aP, bV1, o1, 0,0,0);
    }
    __syncthreads();
  }

  #pragma unroll
  for(int r=0;r<4;r++){
    float li = l[r];
    li += __shfl_xor(li,1,64); li += __shfl_xor(li,2,64);
    li += __shfl_xor(li,4,64); li += __shfl_xor(li,8,64);
    l[r] = li;
  }
  float* Ob = Op + (size_t)ks*S*256;
  #pragma unroll
  for(int r=0;r<4;r++){
    int q = qb + w*16 + g*4 + r;
    Ob[q*256 + h*32 + m]      = o0[r];
    Ob[q*256 + h*32 + 16 + m] = o1[r];
    if(m==0) lp[ks*S*8 + q*8 + h] = l[r];
  }
}

__global__ __launch_bounds__(256) void combine(const float* __restrict__ Op,
                                               const float* __restrict__ lp,
                                               unsigned short* __restrict__ aob, int S){
  int q = blockIdx.x, t = threadIdx.x;
  int h = t >> 5;
  float o = 0.f, l = 0.f;
  #pragma unroll
  for(int s=0;s<KS;s++) o += Op[(size_t)s*S*256 + q*256 + t];
  #pragma unroll
  for(int s=0;s<KS;s++) l += lp[s*S*8 + q*8 + h];
  aob[q*256 + t] = f2bf(o / l);
}

extern "C" void kernel_launch(void* const* d_in, const int* in_sizes, int n_in,
                              void* d_out, int out_size, void* d_ws, size_t ws_size,
                              hipStream_t stream) {
  const float* x   = (const float*)d_in[0];
  const int*   ei  = (const int*)d_in[1];
  const float* W0  = (const float*)d_in[2];
  const float* as0 = (const float*)d_in[3];
  const float* ad0 = (const float*)d_in[4];
  const float* b0  = (const float*)d_in[5];
  const float* W1  = (const float*)d_in[6];
  const float* as1 = (const float*)d_in[7];
  const float* ad1 = (const float*)d_in[8];
  const float* b1  = (const float*)d_in[9];
  const float* W2  = (const float*)d_in[10];
  const float* as2 = (const float*)d_in[11];
  const float* ad2 = (const float*)d_in[12];
  const float* b2  = (const float*)d_in[13];
  const float* g0  = (const float*)d_in[14];
  const float* be0 = (const float*)d_in[15];
  const float* g1  = (const float*)d_in[16];
  const float* be1 = (const float*)d_in[17];
  const float* g2  = (const float*)d_in[18];
  const float* be2 = (const float*)d_in[19];
  const float* wq  = (const float*)d_in[20];
  const float* bq  = (const float*)d_in[21];
  const float* wk  = (const float*)d_in[22];
  const float* bk  = (const float*)d_in[23];
  const float* wv  = (const float*)d_in[24];
  const float* bv  = (const float*)d_in[25];
  const float* wo  = (const float*)d_in[26];
  const float* bo  = (const float*)d_in[27];
  float* out = (float*)d_out;

  const int N = 4096;
  const int E = in_sizes[1] / 2;
  const int Etot = E + N;

  char* p = (char*)d_ws;
  auto alloc = [&](size_t bytes){ char* r = p; p += (bytes + 255) & ~(size_t)255; return r; };

  float* h0   = (float*)alloc(N*512*4);
  float* als  = (float*)alloc(N*4*4);
  float* ald  = (float*)alloc(N*4*4);
  unsigned short* xb   = (unsigned short*)alloc(N*128*2);
  unsigned short* xlb  = (unsigned short*)alloc(N*512*2);
  unsigned short* h0b  = (unsigned short*)alloc(N*512*2);
  unsigned short* h1b  = (unsigned short*)alloc(N*512*2);
  unsigned short* h2b  = (unsigned short*)alloc(N*256*2);
  unsigned short* QKVb = (unsigned short*)alloc((size_t)N*768*2);
  unsigned short* Vt   = (unsigned short*)alloc(256*N*2);
  unsigned short* aob  = (unsigned short*)alloc(N*256*2);
  unsigned short* W0t  = (unsigned short*)alloc(512*128*2);
  unsigned short* W1t  = (unsigned short*)alloc(512*512*2);
  unsigned short* W2t  = (unsigned short*)alloc(256*512*2);
  unsigned short* wqkvt= (unsigned short*)alloc(768*256*2);
  float* bqkv = (float*)alloc(768*4);
  unsigned short* wot  = (unsigned short*)alloc(256*256*2);
  unsigned short* Wsd0 = (unsigned short*)alloc(16*128*2);
  unsigned short* Wsd1 = (unsigned short*)alloc(16*512*2);
  unsigned short* Wsd2 = (unsigned short*)alloc(16*512*2);
  float* Op = (float*)alloc((size_t)KS*N*256*4);
  float* lp = (float*)alloc((size_t)KS*N*8*4);
  int* hist = (int*)alloc(N*4);
  int* wcnt = (int*)alloc(N*4);
  int* rp   = (int*)alloc((N+2)*4);
  int* col  = (int*)alloc(Etot*4);

  // ---------- prep ----------
  prep<<<4865, 256, 0, stream>>>(x, xb, W0, W0t, W1, W1t, W2, W2t,
                                 wq, wk, wv, wqkvt, bq, bk, bv, bqkv, wo, wot);
  make_wsd<<<1152, 256, 0, stream>>>(W0, as0, ad0, Wsd0, W1, as1, ad1, Wsd1, W2, as2, ad2, Wsd2);

  // ---------- CSR build (by destination) ----------
  zero_ints<<<(N+255)/256, 256, 0, stream>>>(hist, N);
  csr_count<<<(Etot+255)/256, 256, 0, stream>>>(ei, E, Etot, hist);
  csr_scan<<<1, 1024, 0, stream>>>(hist, rp, wcnt, N);
  csr_scatter<<<(Etot+255)/256, 256, 0, stream>>>(ei, E, Etot, wcnt, col);

  // ---------- GAT layer 0: 128 -> 4x128 (512) ----------
  gemm_mfma<<<dim3(8, 64), 256, 0, stream>>>(xb, W0t, nullptr, nullptr, xlb, Wsd0, als, ald, N, 128, 512);
  gat_gather_ln<<<N, 256, 0, stream>>>(rp, col, xlb, als, ald, b0, g0, be0,
                                       nullptr, h0, h0b, 512, 7, 1);

  // ---------- GAT layer 1: 512 -> 4x128 (512), residual ----------
  gemm_mfma<<<dim3(8, 64), 256, 0, stream>>>(h0b, W1t, nullptr, nullptr, xlb, Wsd1, als, ald, N, 512, 512);
  gat_gather_ln<<<N, 256, 0, stream>>>(rp, col, xlb, als, ald, b1, g1, be1,
                                       h0, nullptr, h1b, 512, 7, 1);

  // ---------- GAT layer 2: 512 -> 1x256, 1 head, no ELU ----------
  gemm_mfma<<<dim3(4, 64), 256, 0, stream>>>(h1b, W2t, nullptr, nullptr, xlb, Wsd2, als, ald, N, 512, 256);
  gat_gather_ln<<<N, 128, 0, stream>>>(rp, col, xlb, als, ald, b2, g2, be2,
                                       nullptr, nullptr, h2b, 256, 8, 0);

  // ---------- dense MHA (bf16 MFMA, flash-decode, fused QKV) ----------
  gemm_mfma<<<dim3(12, 64), 256, 0, stream>>>(h2b, wqkvt, bqkv, nullptr, QKVb, nullptr, nullptr, nullptr, N, 256, 768);
  transpose_v<<<dim3(N/64, 4), 256, 0, stream>>>(QKVb, Vt, N);
  attention5<<<dim3(N/64, 8, KS), 256, 0, stream>>>(QKVb, Vt, Op, lp, N);
  combine<<<N, 256, 0, stream>>>(Op, lp, aob, N);
  gemm_mfma<<<dim3(4, 64), 256, 0, stream>>>(aob, wot, bo, out, nullptr, nullptr, nullptr, nullptr, N, 256, 256);
}

// Round 8
// 362.151 us; speedup vs baseline: 10.8936x; 1.0601x over previous
//
#include <hip/hip_runtime.h>
#include <math.h>

typedef __attribute__((ext_vector_type(8))) short short8;
typedef __attribute__((ext_vector_type(4))) float float4v;

#define QS 0.2550354f   // (1/sqrt(32)) * log2(e), folded into wq/bq

__device__ __forceinline__ float waveReduceSum(float v){
  #pragma unroll
  for(int o=32;o>0;o>>=1) v += __shfl_down(v,o,64);
  return v;
}

__device__ __forceinline__ unsigned short f2bf(float f){
  unsigned int u = __float_as_uint(f);
  return (unsigned short)((u + 0x7FFFu + ((u>>16)&1u)) >> 16);
}
__device__ __forceinline__ float bf2f(unsigned short u){
  return __uint_as_float(((unsigned int)u)<<16);
}

// ---------------- fused prep: x->bf16 + weight transposes + qkv concat ----------------
__global__ __launch_bounds__(256) void prep(const float* __restrict__ x, unsigned short* __restrict__ xb,
                     const float* __restrict__ W0, unsigned short* __restrict__ W0t,
                     const float* __restrict__ W1, unsigned short* __restrict__ W1t,
                     const float* __restrict__ W2, unsigned short* __restrict__ W2t,
                     const float* __restrict__ wq, const float* __restrict__ wk,
                     const float* __restrict__ wv, unsigned short* __restrict__ wqkvt,
                     const float* __restrict__ bq, const float* __restrict__ bk,
                     const float* __restrict__ bv, float* __restrict__ bqkv,
                     const float* __restrict__ wo, unsigned short* __restrict__ wot){
  int b = blockIdx.x, t = threadIdx.x;
  if(b < 2048){ int i = b*256 + t; xb[i] = f2bf(x[i]); return; }
  if(b == 4864){ bqkv[t] = bq[t]*QS; bqkv[256+t] = bk[t]; bqkv[512+t] = bv[t]; return; }
  const float* src; unsigned short* dst; int K,N,base,roff; float sc = 1.f;
  if(b<2304){src=W0;dst=W0t;K=128;N=512;base=2048;roff=0;}
  else if(b<3328){src=W1;dst=W1t;K=512;N=512;base=2304;roff=0;}
  else if(b<3840){src=W2;dst=W2t;K=512;N=256;base=3328;roff=0;}
  else if(b<4096){src=wq;dst=wqkvt;K=256;N=256;base=3840;roff=0;sc=QS;}
  else if(b<4352){src=wk;dst=wqkvt;K=256;N=256;base=4096;roff=256;}
  else if(b<4608){src=wv;dst=wqkvt;K=256;N=256;base=4352;roff=512;}
  else            {src=wo;dst=wot;K=256;N=256;base=4608;roff=0;}
  int idx = (b-base)*256 + t;
  int k = idx / N, n = idx - k*N;
  dst[(n+roff)*K + k] = f2bf(src[idx]*sc);
}

// --------- Wsd[16][K] bf16: rows 0..H-1 = W@a_s per head, 4..4+H-1 = W@a_d, rest 0 ---------
__global__ __launch_bounds__(256) void make_wsd(const float* __restrict__ W0, const float* __restrict__ as0, const float* __restrict__ ad0, unsigned short* __restrict__ S0,
                                                const float* __restrict__ W1, const float* __restrict__ as1, const float* __restrict__ ad1, unsigned short* __restrict__ S1,
                                                const float* __restrict__ W2, const float* __restrict__ as2, const float* __restrict__ ad2, unsigned short* __restrict__ S2){
  int b = blockIdx.x, t = threadIdx.x;
  const float *W,*as,*ad; unsigned short* S; int K,C,H,k;
  if(b<128){W=W0;as=as0;ad=ad0;S=S0;K=128;C=128;H=4;k=b;}
  else if(b<640){W=W1;as=as1;ad=ad1;S=S1;K=512;C=128;H=4;k=b-128;}
  else {W=W2;as=as2;ad=ad2;S=S2;K=512;C=256;H=1;k=b-640;}
  int D = H*C;
  __shared__ float s1[4], s2[4];
  int lane=t&63, wid=t>>6;
  for(int h=0;h<H;h++){
    float ps=0.f, pd=0.f;
    for(int c=t;c<C;c+=256){
      float wv = W[k*D + h*C + c];
      ps += wv*as[h*C+c];
      pd += wv*ad[h*C+c];
    }
    ps = waveReduceSum(ps); pd = waveReduceSum(pd);
    if(lane==0){ s1[wid]=ps; s2[wid]=pd; }
    __syncthreads();
    if(t==0){
      float u=s1[0]+s1[1]+s1[2]+s1[3], v=s2[0]+s2[1]+s2[2]+s2[3];
      S[h*K+k]=f2bf(u); S[(4+h)*K+k]=f2bf(v);
    }
    __syncthreads();
  }
  if(t==0){
    for(int h=H;h<4;h++){ S[h*K+k]=0; S[(4+h)*K+k]=0; }
    for(int r=8;r<16;r++) S[r*K+k]=0;
  }
}

// ---------------- MFMA bf16 GEMM, zero-LDS; optional fused als/ald ----------------
__global__ __launch_bounds__(256) void gemm_mfma(const unsigned short* __restrict__ A,
                                                 const unsigned short* __restrict__ Bt,
                                                 const float* __restrict__ bias,
                                                 float* __restrict__ C,
                                                 unsigned short* __restrict__ Cb,
                                                 const unsigned short* __restrict__ Wsd,
                                                 float* __restrict__ als,
                                                 float* __restrict__ ald,
                                                 int M, int K, int N){
  int t = threadIdx.x, lane = t & 63, w = t >> 6;
  int m = lane & 15, g = lane >> 4;
  int bm = blockIdx.y * 64, bn = blockIdx.x * 64;

  const unsigned short* Ap = A + (bm + w*16 + m)*K + g*8;
  const unsigned short* Bp = Bt + (bn + m)*K + g*8;
  bool doC = (Wsd != nullptr) && (blockIdx.x == 0);

  float4v acc[4];
  #pragma unroll
  for(int nt=0;nt<4;nt++) acc[nt] = (float4v){0.f,0.f,0.f,0.f};
  float4v acc2 = (float4v){0.f,0.f,0.f,0.f};

  for(int k0=0;k0<K;k0+=32){
    short8 aA = *(const short8*)(Ap + k0);
    #pragma unroll
    for(int nt=0;nt<4;nt++){
      short8 bB = *(const short8*)(Bp + nt*16*K + k0);
      acc[nt] = __builtin_amdgcn_mfma_f32_16x16x32_bf16(aA, bB, acc[nt], 0,0,0);
    }
    if(doC){
      short8 bW = *(const short8*)(Wsd + m*K + g*8 + k0);
      acc2 = __builtin_amdgcn_mfma_f32_16x16x32_bf16(aA, bW, acc2, 0,0,0);
    }
  }
  #pragma unroll
  for(int nt=0;nt<4;nt++){
    int col = bn + nt*16 + m;
    float bv = bias ? bias[col] : 0.f;
    #pragma unroll
    for(int r=0;r<4;r++){
      int row = bm + w*16 + g*4 + r;
      float v = acc[nt][r] + bv;
      if(C)  C[row*N + col]  = v;
      if(Cb) Cb[row*N + col] = f2bf(v);
    }
  }
  if(doC){
    #pragma unroll
    for(int r=0;r<4;r++){
      int row = bm + w*16 + g*4 + r;
      if(m<4)      als[row*4 + m]     = acc2[r];
      else if(m<8) ald[row*4 + (m-4)] = acc2[r];
    }
  }
}

// ---------------- CSR build ----------------
__global__ void zero_ints(int* p, int n){
  int i = blockIdx.x*256 + threadIdx.x;
  if(i<n) p[i]=0;
}

__global__ void csr_count(const int* __restrict__ ei, int E, int Etot,
                          int* __restrict__ hist){
  int e = blockIdx.x*256 + threadIdx.x;
  if(e>=Etot) return;
  int d = (e<E) ? (ei[E+e]&4095) : (e-E);
  atomicAdd(&hist[d], 1);
}

__global__ __launch_bounds__(1024) void csr_scan(const int* __restrict__ hist,
                                                 int* __restrict__ row_ptr,
                                                 int* __restrict__ wcnt, int N){
  __shared__ int sh[1024];
  int t = threadIdx.x;
  int base[4];
  int s = 0;
  #pragma unroll
  for(int i=0;i<4;i++){ base[i]=s; s += hist[t*4+i]; }
  sh[t] = s;
  __syncthreads();
  for(int off=1; off<1024; off<<=1){
    int x = (t>=off) ? sh[t-off] : 0;
    __syncthreads();
    sh[t] += x;
    __syncthreads();
  }
  int excl = (t==0) ? 0 : sh[t-1];
  #pragma unroll
  for(int i=0;i<4;i++){
    row_ptr[t*4+i] = excl + base[i];
    wcnt[t*4+i]    = excl + base[i];
  }
  if(t==1023) row_ptr[N] = excl + s;
}

__global__ void csr_scatter(const int* __restrict__ ei, int E, int Etot,
                            int* __restrict__ wcnt, int* __restrict__ col){
  int e = blockIdx.x*256 + threadIdx.x;
  if(e>=Etot) return;
  int s,d;
  if(e<E){ s=ei[e]&4095; d=ei[E+e]&4095; } else { s=d=e-E; }
  int pos = atomicAdd(&wcnt[d], 1);
  col[pos] = s;
}

// ------- fused GAT gather + softmax + bias + ELU + LayerNorm (+residual) -------
#define CE 128
__global__ void gat_gather_ln(const int* __restrict__ rp,
                              const int* __restrict__ col,
                              const unsigned short* __restrict__ xlb,
                              const float* __restrict__ als,
                              const float* __restrict__ ald,
                              const float* __restrict__ bias,
                              const float* __restrict__ gw,
                              const float* __restrict__ be,
                              const float* __restrict__ res,
                              float* __restrict__ out,
                              unsigned short* __restrict__ outb,
                              int D, int logC, int do_elu){
  int n = blockIdx.x, t = threadIdx.x;
  int c0 = t*2;
  int h = c0 >> logC;            // wave-uniform
  int rowW = D >> 1;
  float4 advv = *(const float4*)(ald + n*4);
  int start = rp[n], end = rp[n+1];
  const unsigned int* xw = (const unsigned int*)xlb;

  __shared__ float pw[CE*4];
  __shared__ int offs[CE];

  float acc0=0.f, acc1=0.f, den=0.f;

  for(int base=start; base<end; base+=CE){
    int cnt = min(CE, end-base);
    __syncthreads();
    if(t < cnt){
      int s = col[base+t];
      offs[t] = s*rowW;
      float4 av = *(const float4*)(als + s*4);
      #pragma unroll
      for(int hh=0;hh<4;hh++){
        float a = ((const float*)&av)[hh] + ((const float*)&advv)[hh];
        a = a>0.f ? a : 0.2f*a;
        pw[t*4+hh] = __expf(a);
      }
    }
    __syncthreads();
    #pragma unroll 4
    for(int j=0;j<cnt;j++){
      float p = pw[j*4+h];
      unsigned int u = xw[offs[j] + t];
      acc0 += p * bf2f((unsigned short)(u & 0xffffu));
      acc1 += p * bf2f((unsigned short)(u >> 16));
      den += p;
    }
  }

  float inv_d = 1.f/(den + 1e-16f);
  float v0 = acc0*inv_d + bias[c0];
  float v1 = acc1*inv_d + bias[c0+1];
  if(do_elu){
    v0 = v0>0.f ? v0 : expm1f(v0);
    v1 = v1>0.f ? v1 : expm1f(v1);
  }
  __shared__ float sh[4];
  int lane=t&63, wid=t>>6, nw = blockDim.x>>6;
  float sum = waveReduceSum(v0+v1);
  if(lane==0) sh[wid]=sum;
  __syncthreads();
  float mean = 0.f;
  for(int i=0;i<nw;i++) mean += sh[i];
  mean /= (float)D;
  __syncthreads();
  float d0 = v0-mean, d1 = v1-mean;
  float vs = waveReduceSum(d0*d0 + d1*d1);
  if(lane==0) sh[wid]=vs;
  __syncthreads();
  float var = 0.f;
  for(int i=0;i<nw;i++) var += sh[i];
  var /= (float)D;
  float inv = rsqrtf(var + 1e-5f);
  float y0 = d0*inv*gw[c0]   + be[c0];
  float y1 = d1*inv*gw[c0+1] + be[c0+1];
  if(res){ float2 rv = *(const float2*)(res + n*D + c0); y0 += rv.x; y1 += rv.y; }
  if(out) *(float2*)(out + n*D + c0) = make_float2(y0, y1);
  if(outb) ((unsigned int*)outb)[n*rowW + t] =
      (unsigned int)f2bf(y0) | ((unsigned int)f2bf(y1) << 16);
}

// --------- V transpose: QKV[:,512:768] bf16 [S,768] -> Vt bf16 [256,S] ---------
__global__ __launch_bounds__(256) void transpose_v(const unsigned short* __restrict__ QKV,
                                                   unsigned short* __restrict__ Vt, int S){
  __shared__ unsigned short tile[64][72];
  int bs = blockIdx.x*64;
  int bd = blockIdx.y*64;
  int t = threadIdx.x;
  int r8 = t>>3, c8 = (t&7)*8;
  #pragma unroll
  for(int it=0; it<2; it++){
    int row = r8 + it*32;
    short8 v = *(const short8*)(QKV + (bs+row)*768 + 512 + bd + c8);
    *(short8*)&tile[row][c8] = v;
  }
  __syncthreads();
  #pragma unroll
  for(int it=0; it<2; it++){
    int drow = r8 + it*32;
    short8 o;
    #pragma unroll
    for(int j=0;j<8;j++) o[j] = (short)tile[c8+j][drow];
    *(short8*)(Vt + (bd+drow)*S + bs + c8) = o;
  }
}

// --------- MFMA bf16 MHA, flash-decode: block=(64q, head, ksplit) ---------
// bf16 Ps (R6 geometry), double-buffered Vs (1 barrier/tile), register
// prefetch of next-V and all bK before the barrier. Q pre-scaled -> exp2.
#define KS 4
__global__ __launch_bounds__(256) void attention6(const unsigned short* __restrict__ QKV,
                                                  const unsigned short* __restrict__ Vt,
                                                  float* __restrict__ Op,
                                                  float* __restrict__ lp, int S){
  const int RS = 768;
  int qb = blockIdx.x * 64;
  int h  = blockIdx.y;
  int ks = blockIdx.z;
  int t  = threadIdx.x;
  int lane = t & 63, w = t >> 6;
  int m = lane & 15, g = lane >> 4;

  __shared__ unsigned short Ps[64*72];      // [q][key] bf16, stride 72
  __shared__ unsigned short Vs[2][32*72];   // [dim][key] bf16, double-buffered

  short8 aQ = *(const short8*)(QKV + (qb + w*16 + m)*RS + h*32 + g*8);

  float4v o0 = {0.f,0.f,0.f,0.f}, o1 = {0.f,0.f,0.f,0.f};
  float l[4] = {0.f,0.f,0.f,0.f};

  int r8 = t>>3, c8 = (t&7)*8;
  int kA = ks*(S/KS), kB = kA + S/KS;

  // preload first V tile
  short8 vreg = *(const short8*)(Vt + (h*32 + r8)*S + kA + c8);

  int buf = 0;
  for(int kt=kA; kt<kB; kt+=64, buf^=1){
    // commit prefetched V, then prefetch next tile's K and V before the barrier
    *(short8*)&Vs[buf][r8*72 + c8] = vreg;
    const unsigned short* Kp = QKV + (kt + m)*RS + 256 + h*32 + g*8;
    short8 bK0 = *(const short8*)(Kp);
    short8 bK1 = *(const short8*)(Kp + 16*RS);
    short8 bK2 = *(const short8*)(Kp + 32*RS);
    short8 bK3 = *(const short8*)(Kp + 48*RS);
    if(kt+64 < kB) vreg = *(const short8*)(Vt + (h*32 + r8)*S + (kt+64) + c8);
    __syncthreads();

    // S strip (16 q x 64 k per wave) -> exp2 -> Ps (wave-private rows)
    short8 bKs[4] = {bK0,bK1,bK2,bK3};
    #pragma unroll
    for(int nt=0;nt<4;nt++){
      float4v acc = {0.f,0.f,0.f,0.f};
      acc = __builtin_amdgcn_mfma_f32_16x16x32_bf16(aQ, bKs[nt], acc, 0,0,0);
      #pragma unroll
      for(int r=0;r<4;r++){
        float pe = exp2f(acc[r]);
        l[r] += pe;
        Ps[(w*16 + g*4 + r)*72 + nt*16 + m] =
            (unsigned short)((__float_as_uint(pe) + 0x8000u) >> 16);
      }
    }

    // O strip += P @ V
    #pragma unroll
    for(int kh=0;kh<2;kh++){
      short8 aP  = *(const short8*)&Ps[(w*16 + m)*72 + kh*32 + g*8];
      short8 bV0 = *(const short8*)&Vs[buf][(m)*72    + kh*32 + g*8];
      short8 bV1 = *(const short8*)&Vs[buf][(16+m)*72 + kh*32 + g*8];
      o0 = __builtin_amdgcn_mfma_f32_16x16x32_bf16(aP, bV0, o0, 0,0,0);
      o1 = __builtin_amdgcn_mfma_f32_16x16x32_bf16(aP, bV1, o1, 0,0,0);
    }
    // no trailing barrier: next iter writes the other Vs buffer
  }

  #pragma unroll
  for(int r=0;r<4;r++){
    float li = l[r];
    li += __shfl_xor(li,1,64); li += __shfl_xor(li,2,64);
    li += __shfl_xor(li,4,64); li += __shfl_xor(li,8,64);
    l[r] = li;
  }
  float* Ob = Op + (size_t)ks*S*256;
  #pragma unroll
  for(int r=0;r<4;r++){
    int q = qb + w*16 + g*4 + r;
    Ob[q*256 + h*32 + m]      = o0[r];
    Ob[q*256 + h*32 + 16 + m] = o1[r];
    if(m==0) lp[ks*S*8 + q*8 + h] = l[r];
  }
}

__global__ __launch_bounds__(256) void combine(const float* __restrict__ Op,
                                               const float* __restrict__ lp,
                                               unsigned short* __restrict__ aob, int S){
  int q = blockIdx.x, t = threadIdx.x;
  int h = t >> 5;
  float o = 0.f, l = 0.f;
  #pragma unroll
  for(int s=0;s<KS;s++) o += Op[(size_t)s*S*256 + q*256 + t];
  #pragma unroll
  for(int s=0;s<KS;s++) l += lp[s*S*8 + q*8 + h];
  aob[q*256 + t] = f2bf(o / l);
}

extern "C" void kernel_launch(void* const* d_in, const int* in_sizes, int n_in,
                              void* d_out, int out_size, void* d_ws, size_t ws_size,
                              hipStream_t stream) {
  const float* x   = (const float*)d_in[0];
  const int*   ei  = (const int*)d_in[1];
  const float* W0  = (const float*)d_in[2];
  const float* as0 = (const float*)d_in[3];
  const float* ad0 = (const float*)d_in[4];
  const float* b0  = (const float*)d_in[5];
  const float* W1  = (const float*)d_in[6];
  const float* as1 = (const float*)d_in[7];
  const float* ad1 = (const float*)d_in[8];
  const float* b1  = (const float*)d_in[9];
  const float* W2  = (const float*)d_in[10];
  const float* as2 = (const float*)d_in[11];
  const float* ad2 = (const float*)d_in[12];
  const float* b2  = (const float*)d_in[13];
  const float* g0  = (const float*)d_in[14];
  const float* be0 = (const float*)d_in[15];
  const float* g1  = (const float*)d_in[16];
  const float* be1 = (const float*)d_in[17];
  const float* g2  = (const float*)d_in[18];
  const float* be2 = (const float*)d_in[19];
  const float* wq  = (const float*)d_in[20];
  const float* bq  = (const float*)d_in[21];
  const float* wk  = (const float*)d_in[22];
  const float* bk  = (const float*)d_in[23];
  const float* wv  = (const float*)d_in[24];
  const float* bv  = (const float*)d_in[25];
  const float* wo  = (const float*)d_in[26];
  const float* bo  = (const float*)d_in[27];
  float* out = (float*)d_out;

  const int N = 4096;
  const int E = in_sizes[1] / 2;
  const int Etot = E + N;

  char* p = (char*)d_ws;
  auto alloc = [&](size_t bytes){ char* r = p; p += (bytes + 255) & ~(size_t)255; return r; };

  float* h0   = (float*)alloc(N*512*4);
  float* als  = (float*)alloc(N*4*4);
  float* ald  = (float*)alloc(N*4*4);
  unsigned short* xb   = (unsigned short*)alloc(N*128*2);
  unsigned short* xlb  = (unsigned short*)alloc(N*512*2);
  unsigned short* h0b  = (unsigned short*)alloc(N*512*2);
  unsigned short* h1b  = (unsigned short*)alloc(N*512*2);
  unsigned short* h2b  = (unsigned short*)alloc(N*256*2);
  unsigned short* QKVb = (unsigned short*)alloc((size_t)N*768*2);
  unsigned short* Vt   = (unsigned short*)alloc(256*N*2);
  unsigned short* aob  = (unsigned short*)alloc(N*256*2);
  unsigned short* W0t  = (unsigned short*)alloc(512*128*2);
  unsigned short* W1t  = (unsigned short*)alloc(512*512*2);
  unsigned short* W2t  = (unsigned short*)alloc(256*512*2);
  unsigned short* wqkvt= (unsigned short*)alloc(768*256*2);
  float* bqkv = (float*)alloc(768*4);
  unsigned short* wot  = (unsigned short*)alloc(256*256*2);
  unsigned short* Wsd0 = (unsigned short*)alloc(16*128*2);
  unsigned short* Wsd1 = (unsigned short*)alloc(16*512*2);
  unsigned short* Wsd2 = (unsigned short*)alloc(16*512*2);
  float* Op = (float*)alloc((size_t)KS*N*256*4);
  float* lp = (float*)alloc((size_t)KS*N*8*4);
  int* hist = (int*)alloc(N*4);
  int* wcnt = (int*)alloc(N*4);
  int* rp   = (int*)alloc((N+2)*4);
  int* col  = (int*)alloc(Etot*4);

  // ---------- prep ----------
  prep<<<4865, 256, 0, stream>>>(x, xb, W0, W0t, W1, W1t, W2, W2t,
                                 wq, wk, wv, wqkvt, bq, bk, bv, bqkv, wo, wot);
  make_wsd<<<1152, 256, 0, stream>>>(W0, as0, ad0, Wsd0, W1, as1, ad1, Wsd1, W2, as2, ad2, Wsd2);

  // ---------- CSR build (by destination) ----------
  zero_ints<<<(N+255)/256, 256, 0, stream>>>(hist, N);
  csr_count<<<(Etot+255)/256, 256, 0, stream>>>(ei, E, Etot, hist);
  csr_scan<<<1, 1024, 0, stream>>>(hist, rp, wcnt, N);
  csr_scatter<<<(Etot+255)/256, 256, 0, stream>>>(ei, E, Etot, wcnt, col);

  // ---------- GAT layer 0: 128 -> 4x128 (512) ----------
  gemm_mfma<<<dim3(8, 64), 256, 0, stream>>>(xb, W0t, nullptr, nullptr, xlb, Wsd0, als, ald, N, 128, 512);
  gat_gather_ln<<<N, 256, 0, stream>>>(rp, col, xlb, als, ald, b0, g0, be0,
                                       nullptr, h0, h0b, 512, 7, 1);

  // ---------- GAT layer 1: 512 -> 4x128 (512), residual ----------
  gemm_mfma<<<dim3(8, 64), 256, 0, stream>>>(h0b, W1t, nullptr, nullptr, xlb, Wsd1, als, ald, N, 512, 512);
  gat_gather_ln<<<N, 256, 0, stream>>>(rp, col, xlb, als, ald, b1, g1, be1,
                                       h0, nullptr, h1b, 512, 7, 1);

  // ---------- GAT layer 2: 512 -> 1x256, 1 head, no ELU ----------
  gemm_mfma<<<dim3(4, 64), 256, 0, stream>>>(h1b, W2t, nullptr, nullptr, xlb, Wsd2, als, ald, N, 512, 256);
  gat_gather_ln<<<N, 128, 0, stream>>>(rp, col, xlb, als, ald, b2, g2, be2,
                                       nullptr, nullptr, h2b, 256, 8, 0);

  // ---------- dense MHA (bf16 MFMA, flash-decode, fused QKV) ----------
  gemm_mfma<<<dim3(12, 64), 256, 0, stream>>>(h2b, wqkvt, bqkv, nullptr, QKVb, nullptr, nullptr, nullptr, N, 256, 768);
  transpose_v<<<dim3(N/64, 4), 256, 0, stream>>>(QKVb, Vt, N);
  attention6<<<dim3(N/64, 8, KS), 256, 0, stream>>>(QKVb, Vt, Op, lp, N);
  combine<<<N, 256, 0, stream>>>(Op, lp, aob, N);
  gemm_mfma<<<dim3(4, 64), 256, 0, stream>>>(aob, wot, bo, out, nullptr, nullptr, nullptr, nullptr, N, 256, 256);
}